// Round 1
// baseline (358.437 us; speedup 1.0000x reference)
//
#include <hip/hip_runtime.h>
#include <math.h>

typedef unsigned short u16;
typedef unsigned int   u32;
typedef short s16x8 __attribute__((ext_vector_type(8)));
typedef float f32x4 __attribute__((ext_vector_type(4)));

#define N_TOK 2048
#define DIM   512
#define HID   2048
#define NE    16
#define NG    4
#define EPG   4
#define MAXT  2048

#define BM 64
#define BN 128
#define BK 64

// ---- workspace layout (bytes) ----
#define WS_CNT    0                              // 16 ints
#define WS_OFF    128                            // 17 ints
#define WS_TOKIDX 256                            // 16*2048 ints
#define WS_TW     (WS_TOKIDX + NE*MAXT*4)        // twT[e][t]: 16*2048 f32
#define WS_XB     (WS_TW + N_TOK*NE*4)           // 2048*512 u16 (bf16 x)
#define WS_HBUF   (WS_XB + (size_t)N_TOK*DIM*2)  // 8192*2048 u16
#define WS_W1T    (WS_HBUF + (size_t)8192*HID*2) // 16*2048*512 u16 (bf16 W1^T [e][n][k])
#define WS_W3T    (WS_W1T + (size_t)NE*HID*DIM*2)
#define WS_W2T    (WS_W3T + (size_t)NE*HID*DIM*2) // 16*512*2048 u16 (bf16 W2^T [e][n][k])
#define WS_SLOT   (WS_W2T + (size_t)NE*DIM*HID*2) // slot_of[e][t]: 16*2048 ints
// buf2 (8192*512 f32 = 16.8 MB) aliases W1T: W1T is dead once gemm1 completes,
// buf2 is written by gemm2 (after gemm1) and read by gather. Safe within one call
// and across graph replays (transpose rewrites W1T first each call).
#define WS_BUF2   WS_W1T

__device__ __forceinline__ int* ws_i32(void* ws, size_t off) { return (int*)((char*)ws + off); }

__device__ __forceinline__ u16 f2b(float f) {   // fp32 -> bf16 RNE
    union { float f; u32 i; } v; v.f = f;
    u32 b = v.i;
    u32 r = b + 0x7FFFu + ((b >> 16) & 1u);
    return (u16)(r >> 16);
}

// async global->LDS, 16B/lane; LDS side is wave-uniform base + lane*16
__device__ __forceinline__ void gl_lds16(const u16* g, u16* l) {
    __builtin_amdgcn_global_load_lds((const __attribute__((address_space(1))) void*)g,
                                     (__attribute__((address_space(3))) void*)l, 16, 0, 0);
}

// ---------------- routing: 4 waves/block, one wave per token; NO atomics ----------------
__global__ __launch_bounds__(256) void routing_kernel(
    const float* __restrict__ x, const float* __restrict__ Wr, const float* __restrict__ br,
    const float* __restrict__ Wgate, const float* __restrict__ bgate, void* ws)
{
    int tid = threadIdx.x;
    int t = blockIdx.x * 4 + (tid >> 6);
    int lane = tid & 63;

    float xl[8];
    {
        const float4* xr = (const float4*)(x + (size_t)t*DIM + lane*8);
        float4 a = xr[0], b = xr[1];
        xl[0]=a.x; xl[1]=a.y; xl[2]=a.z; xl[3]=a.w;
        xl[4]=b.x; xl[5]=b.y; xl[6]=b.z; xl[7]=b.w;
    }

    {
        union { u16 h[8]; uint4 q; } pk;
        #pragma unroll
        for (int i = 0; i < 8; i++) pk.h[i] = f2b(xl[i]);
        u16* xb = (u16*)((char*)ws + WS_XB);
        *(uint4*)(xb + (size_t)t*DIM + lane*8) = pk.q;
    }

    float gl[NG] = {0.f,0.f,0.f,0.f};
    float el[NE];
    #pragma unroll
    for (int e = 0; e < NE; e++) el[e] = 0.f;

    {
        const float4* Wr4 = (const float4*)Wr;
        #pragma unroll
        for (int c = 0; c < 8; c++) {
            float4 w = Wr4[lane*8 + c];
            gl[0] += xl[c]*w.x; gl[1] += xl[c]*w.y;
            gl[2] += xl[c]*w.z; gl[3] += xl[c]*w.w;
        }
    }
    {
        const float4* Wg4 = (const float4*)Wgate;
        #pragma unroll
        for (int g = 0; g < NG; g++) {
            #pragma unroll
            for (int c = 0; c < 8; c++) {
                float4 w = Wg4[(size_t)g*DIM + lane*8 + c];
                el[g*4+0] += xl[c]*w.x; el[g*4+1] += xl[c]*w.y;
                el[g*4+2] += xl[c]*w.z; el[g*4+3] += xl[c]*w.w;
            }
        }
    }

    #pragma unroll
    for (int g = 0; g < NG; g++)
        #pragma unroll
        for (int s = 32; s; s >>= 1) gl[g] += __shfl_xor(gl[g], s);
    #pragma unroll
    for (int e = 0; e < NE; e++)
        #pragma unroll
        for (int s = 32; s; s >>= 1) el[e] += __shfl_xor(el[e], s);

    if (lane != 0) return;

    float gp[NG];
    float mx = -1e30f;
    #pragma unroll
    for (int g = 0; g < NG; g++) { gl[g] += br[g]; mx = fmaxf(mx, gl[g]); }
    float sum = 0.f;
    #pragma unroll
    for (int g = 0; g < NG; g++) { gp[g] = expf(gl[g] - mx); sum += gp[g]; }
    #pragma unroll
    for (int g = 0; g < NG; g++) gp[g] /= sum;

    int i0 = 0;
    #pragma unroll
    for (int g = 1; g < NG; g++) if (gp[g] > gp[i0]) i0 = g;
    int i1 = -1;
    #pragma unroll
    for (int g = 0; g < NG; g++) { if (g == i0) continue; if (i1 < 0 || gp[g] > gp[i1]) i1 = g; }

    bool act1 = (gp[i0] + gp[i1]) <= 0.9f;
    float mp0 = gp[i0], mp1 = act1 ? gp[i1] : 0.f;
    float inv = 1.f / (mp0 + mp1 + 1e-9f);
    float wg[NG] = {0.f,0.f,0.f,0.f};
    wg[i0] = mp0 * inv;
    wg[i1] = mp1 * inv;

    float tw[NE];
    #pragma unroll
    for (int g = 0; g < NG; g++) {
        float ep[EPG];
        float emx = -1e30f;
        #pragma unroll
        for (int j = 0; j < EPG; j++) {
            float v = el[g*4 + j] + bgate[g*4 + j];
            ep[j] = v; emx = fmaxf(emx, v);
        }
        float es = 0.f;
        #pragma unroll
        for (int j = 0; j < EPG; j++) { ep[j] = expf(ep[j] - emx); es += ep[j]; }
        #pragma unroll
        for (int j = 0; j < EPG; j++) ep[j] /= es;

        int j0 = 0;
        #pragma unroll
        for (int j = 1; j < EPG; j++) if (ep[j] > ep[j0]) j0 = j;
        int j1 = -1;
        #pragma unroll
        for (int j = 0; j < EPG; j++) { if (j == j0) continue; if (j1 < 0 || ep[j] > ep[j1]) j1 = j; }

        bool ea1 = (ep[j0] + ep[j1]) <= 0.9f;
        float e0 = ep[j0], e1 = ea1 ? ep[j1] : 0.f;
        float einv = 1.f / (e0 + e1 + 1e-9f);
        float we[EPG] = {0.f,0.f,0.f,0.f};
        we[j0] = e0 * einv;
        we[j1] = e1 * einv;
        #pragma unroll
        for (int j = 0; j < EPG; j++) tw[g*4 + j] = wg[g] * we[j] * 0.5f;   // SCALE = 1/sqrt(4)
    }

    float* twT = (float*)((char*)ws + WS_TW);
    #pragma unroll
    for (int e = 0; e < NE; e++) twT[(size_t)e*N_TOK + t] = tw[e];
}

// ---- expert lists + scan + slot map: 16 waves, two ballot passes, no atomics ----
__global__ __launch_bounds__(1024) void expert_scan_kernel(void* ws)
{
    int tid = threadIdx.x;
    int e = tid >> 6, lane = tid & 63;
    const float* twT = (const float*)((char*)ws + WS_TW) + (size_t)e*N_TOK;
    int* tok = ws_i32(ws, WS_TOKIDX) + e*MAXT;
    __shared__ int scnt[NE];
    __shared__ int soff[NE+1];

    float v[32];
    #pragma unroll
    for (int r = 0; r < 32; r++) v[r] = twT[r*64 + lane];

    unsigned long long lanemask = (1ull << lane) - 1ull;
    int base = 0;
    #pragma unroll
    for (int r = 0; r < 32; r++) {
        bool a = v[r] > 0.f;
        unsigned long long m = __ballot(a);
        if (a) tok[base + __popcll(m & lanemask)] = r*64 + lane;
        base += __popcll(m);
    }
    if (lane == 0) scnt[e] = base;
    __syncthreads();
    if (tid == 0) {
        int* cnt = ws_i32(ws, WS_CNT);
        int* off = ws_i32(ws, WS_OFF);
        int s = 0;
        for (int i = 0; i < NE; i++) { cnt[i] = scnt[i]; off[i] = s; soff[i] = s; s += scnt[i]; }
        off[NE] = s; soff[NE] = s;
    }
    __syncthreads();

    // pass 2: global slot per (e,t), -1 if inactive
    int* slot_of = ws_i32(ws, WS_SLOT) + e*N_TOK;
    int base2 = soff[e];
    #pragma unroll
    for (int r = 0; r < 32; r++) {
        bool a = v[r] > 0.f;
        unsigned long long m = __ballot(a);
        int pre = __popcll(m & lanemask);
        slot_of[r*64 + lane] = a ? (base2 + pre) : -1;
        base2 += __popcll(m);
    }
}

// ---- convert+transpose: fp32 [e][K][N] -> bf16 [e][N][K] ----
// v2: persistent double-buffered pipeline. 512 blocks (2/CU, one round), each owns
// 6 tiles of 128k x 128n. Per tile: pack regs->LDS(buf), ISSUE next tile's global
// loads, then lgkmcnt(0)-only barrier (raw s_barrier — global loads stay in flight
// across it, unlike __syncthreads' vmcnt(0) drain), then ds_read+store while the
// next tile's reads land. One barrier/tile is safe: T[b] written at it is last
// read at it-2, separated by the it-1 barrier.
// LDS tile [128n][128k] u16 with 8B-chunk XOR swizzle c' = c ^ ((n>>2 & 15)<<1)
// (even mask keeps b128 read pairs adjacent). Output layout plain [n][k] — GEMMs'
// pre-swizzled-source staging unchanged.
__global__ __launch_bounds__(1024) void transpose_all_kernel(
    const float* __restrict__ W1, const float* __restrict__ W3,
    const float* __restrict__ W2, void* ws)
{
    __shared__ u16 T[2][128*128];   // 2 x 32 KB
    int tid = threadIdx.x;
    int j = tid & 31, i0 = tid >> 5;     // j: n-micro (coalesced read), i0: k-micro
    int tg0 = blockIdx.x * 6;            // 512 blocks x 6 tiles = 3072 tiles

    const float* src; u16* dst; int K, N, k0, n0;
    float4 v0, v1, v2, v3;

    auto setup = [&](int tg) {
        int z = tg >> 6, w = tg & 63;    // z: (mat,e); w: tile within matrix
        int mat = z >> 4, e = z & 15;
        if (mat == 0)      { src = W1; dst = (u16*)((char*)ws + WS_W1T); }
        else if (mat == 1) { src = W3; dst = (u16*)((char*)ws + WS_W3T); }
        else               { src = W2; dst = (u16*)((char*)ws + WS_W2T); }
        if (mat < 2) { K = DIM; N = HID; k0 = (w & 3)  << 7; n0 = (w >> 2) << 7; }
        else         { K = HID; N = DIM; k0 = (w & 15) << 7; n0 = (w >> 4) << 7; }
        src += (size_t)e*K*N + (size_t)(k0 + 4*i0)*N + n0 + 4*j;
        dst += (size_t)e*N*K;
    };
    auto issue_loads = [&]() {           // 4 x float4, 512B-contiguous rows
        v0 = *(const float4*)(src);
        v1 = *(const float4*)(src + N);
        v2 = *(const float4*)(src + 2*N);
        v3 = *(const float4*)(src + 3*N);
    };

    setup(tg0);
    issue_loads();

    for (int it = 0; it < 6; ++it) {
        // stash current tile's store params before setup() advances to next tile
        u16* dstc = dst; int Kc = K, k0c = k0, n0c = n0;
        u16* Tb = &T[it & 1][0];

        // regs -> LDS (4x4 micro-transpose), swizzled chunk pc = i0 ^ ((j&15)<<1)
        int pc = 4 * (i0 ^ ((j & 15) << 1));
        union { u16 h[4]; uint2 q; } p;
        p.h[0]=f2b(v0.x); p.h[1]=f2b(v1.x); p.h[2]=f2b(v2.x); p.h[3]=f2b(v3.x);
        *(uint2*)(&Tb[(4*j+0)*128 + pc]) = p.q;
        p.h[0]=f2b(v0.y); p.h[1]=f2b(v1.y); p.h[2]=f2b(v2.y); p.h[3]=f2b(v3.y);
        *(uint2*)(&Tb[(4*j+1)*128 + pc]) = p.q;
        p.h[0]=f2b(v0.z); p.h[1]=f2b(v1.z); p.h[2]=f2b(v2.z); p.h[3]=f2b(v3.z);
        *(uint2*)(&Tb[(4*j+2)*128 + pc]) = p.q;
        p.h[0]=f2b(v0.w); p.h[1]=f2b(v1.w); p.h[2]=f2b(v2.w); p.h[3]=f2b(v3.w);
        *(uint2*)(&Tb[(4*j+3)*128 + pc]) = p.q;

        // prefetch next tile's global loads — stay in flight across the barrier
        if (it + 1 < 6) { setup(tg0 + it + 1); issue_loads(); }

        // drain LDS writes only; do NOT drain vmcnt (that's __syncthreads' stall)
        asm volatile("s_waitcnt lgkmcnt(0)" ::: "memory");
        __builtin_amdgcn_s_barrier();

        // LDS -> global: 2 b128 per thread, 256B-contiguous store segments per n-row
        #pragma unroll
        for (int ph = 0; ph < 2; ++ph) {
            int idx = tid + ph*1024;
            int nr = idx >> 4, sg = idx & 15;
            int cp = (2*sg) ^ (((nr >> 2) & 15) << 1);
            *(s16x8*)(dstc + (size_t)(n0c + nr)*Kc + k0c + sg*8) = *(const s16x8*)(&Tb[nr*128 + 4*cp]);
        }
    }
}

// ---------------- GEMM1: hbuf = bf16( silu(X W1) * (X W3) ), async-LDS staging ----------------
__global__ __launch_bounds__(256) void gemm1_fast(void* ws)
{
    int e  = blockIdx.z;
    const int* cnt = ws_i32(ws, WS_CNT);
    int ce = cnt[e];
    int m0 = blockIdx.y * BM;
    if (m0 >= ce) return;
    int n0 = blockIdx.x * BN;

    const int* off = ws_i32(ws, WS_OFF);
    const int* tok = ws_i32(ws, WS_TOKIDX) + e*MAXT;
    const u16* xb  = (const u16*)((char*)ws + WS_XB);
    const u16* W1T = (const u16*)((char*)ws + WS_W1T) + (size_t)e*HID*DIM;  // [n][k]
    const u16* W3T = (const u16*)((char*)ws + WS_W3T) + (size_t)e*HID*DIM;
    u16* hbuf = (u16*)((char*)ws + WS_HBUF);
    int obase = off[e] + m0;

    __shared__ u16 As[BM*BK];        // swizzled [m][k]
    __shared__ u16 Bs0[BN*BK];       // swizzled [n][k]
    __shared__ u16 Bs1[BN*BK];
    __shared__ int rowtok[BM];

    int tid = threadIdx.x;
    if (tid < BM) {
        int m = m0 + tid;
        rowtok[tid] = tok[m < ce ? m : (ce - 1)];
    }
    __syncthreads();

    int wave = tid >> 6, lane = tid & 63;
    int quad = lane >> 4, l16 = lane & 15;
    int swz  = l16 & 7;
    int r8 = lane >> 3, sg = lane & 7;
    int swk = ((sg ^ r8) << 3);      // swizzle folded into global k-offset

    const u16* arow0 = xb + (size_t)rowtok[wave*16 + r8]*DIM + swk;
    const u16* arow1 = xb + (size_t)rowtok[wave*16 + 8 + r8]*DIM + swk;
    const u16* b1row[4]; const u16* b3row[4];
    #pragma unroll
    for (int i = 0; i < 4; i++) {
        size_t nr = (size_t)(n0 + wave*32 + i*8 + r8)*DIM + swk;
        b1row[i] = W1T + nr;
        b3row[i] = W3T + nr;
    }

    f32x4 acc1[4][2], acc3[4][2];
    #pragma unroll
    for (int mt = 0; mt < 4; mt++)
        #pragma unroll
        for (int nt = 0; nt < 2; nt++) {
            acc1[mt][nt] = (f32x4){0.f,0.f,0.f,0.f};
            acc3[mt][nt] = (f32x4){0.f,0.f,0.f,0.f};
        }

    for (int k0 = 0; k0 < DIM; k0 += BK) {
        gl_lds16(arow0 + k0, &As[(wave*16)*BK]);
        gl_lds16(arow1 + k0, &As[(wave*16 + 8)*BK]);
        #pragma unroll
        for (int i = 0; i < 4; i++) {
            gl_lds16(b1row[i] + k0, &Bs0[(wave*32 + i*8)*BK]);
            gl_lds16(b3row[i] + k0, &Bs1[(wave*32 + i*8)*BK]);
        }
        __syncthreads();

        #pragma unroll
        for (int kk = 0; kk < BK; kk += 32) {
            int jj = (kk >> 3) + quad;
            int so = ((jj ^ swz) << 3);
            s16x8 af[4];
            #pragma unroll
            for (int mt = 0; mt < 4; mt++)
                af[mt] = *(const s16x8*)(&As[(mt*16 + l16)*BK + so]);
            #pragma unroll
            for (int nt = 0; nt < 2; nt++) {
                int n = wave*32 + nt*16 + l16;
                s16x8 b1 = *(const s16x8*)(&Bs0[n*BK + so]);
                s16x8 b3 = *(const s16x8*)(&Bs1[n*BK + so]);
                #pragma unroll
                for (int mt = 0; mt < 4; mt++) {
                    acc1[mt][nt] = __builtin_amdgcn_mfma_f32_16x16x32_bf16(af[mt], b1, acc1[mt][nt], 0, 0, 0);
                    acc3[mt][nt] = __builtin_amdgcn_mfma_f32_16x16x32_bf16(af[mt], b3, acc3[mt][nt], 0, 0, 0);
                }
            }
        }
        __syncthreads();
    }

    #pragma unroll
    for (int mt = 0; mt < 4; mt++) {
        #pragma unroll
        for (int r = 0; r < 4; r++) {
            int row = mt*16 + quad*4 + r;
            if (m0 + row < ce) {
                #pragma unroll
                for (int nt = 0; nt < 2; nt++) {
                    float a = acc1[mt][nt][r];
                    float b = acc3[mt][nt][r];
                    float h = (a / (1.f + expf(-a))) * b;
                    int col = wave*32 + nt*16 + l16;
                    hbuf[(size_t)(obase + row)*HID + n0 + col] = f2b(h);
                }
            }
        }
    }
}

// ---------------- GEMM2: buf2 = tw * (h W2), plain stores (no atomics) ----------------
__global__ __launch_bounds__(256) void gemm2_fast(void* ws)
{
    int e  = blockIdx.z;
    const int* cnt = ws_i32(ws, WS_CNT);
    int ce = cnt[e];
    int m0 = blockIdx.y * BM;
    if (m0 >= ce) return;
    int n0 = blockIdx.x * BN;

    const int* off = ws_i32(ws, WS_OFF);
    const int* tok = ws_i32(ws, WS_TOKIDX) + e*MAXT;
    const float* twT = (const float*)((char*)ws + WS_TW);
    const u16* hbuf = (const u16*)((char*)ws + WS_HBUF);
    const u16* W2T = (const u16*)((char*)ws + WS_W2T) + (size_t)e*DIM*HID;  // [n=512][k=2048]
    float* buf2 = (float*)((char*)ws + WS_BUF2);
    int abase = off[e] + m0;
    int total = off[NE];

    __shared__ u16 As[BM*BK];
    __shared__ u16 Bs[BN*BK];

    int tid = threadIdx.x;
    int wave = tid >> 6, lane = tid & 63;
    int quad = lane >> 4, l16 = lane & 15;
    int swz  = l16 & 7;
    int r8 = lane >> 3, sg = lane & 7;
    int swk = ((sg ^ r8) << 3);

    int ar0 = abase + wave*16 + r8;      if (ar0 > total - 1) ar0 = total - 1;
    int ar1 = abase + wave*16 + 8 + r8;  if (ar1 > total - 1) ar1 = total - 1;
    const u16* arow0 = hbuf + (size_t)ar0*HID + swk;
    const u16* arow1 = hbuf + (size_t)ar1*HID + swk;
    const u16* brow[4];
    #pragma unroll
    for (int i = 0; i < 4; i++)
        brow[i] = W2T + (size_t)(n0 + wave*32 + i*8 + r8)*HID + swk;

    f32x4 acc[4][2];
    #pragma unroll
    for (int mt = 0; mt < 4; mt++)
        #pragma unroll
        for (int nt = 0; nt < 2; nt++) acc[mt][nt] = (f32x4){0.f,0.f,0.f,0.f};

    for (int k0 = 0; k0 < HID; k0 += BK) {
        gl_lds16(arow0 + k0, &As[(wave*16)*BK]);
        gl_lds16(arow1 + k0, &As[(wave*16 + 8)*BK]);
        #pragma unroll
        for (int i = 0; i < 4; i++)
            gl_lds16(brow[i] + k0, &Bs[(wave*32 + i*8)*BK]);
        __syncthreads();

        #pragma unroll
        for (int kk = 0; kk < BK; kk += 32) {
            int jj = (kk >> 3) + quad;
            int so = ((jj ^ swz) << 3);
            s16x8 af[4];
            #pragma unroll
            for (int mt = 0; mt < 4; mt++)
                af[mt] = *(const s16x8*)(&As[(mt*16 + l16)*BK + so]);
            #pragma unroll
            for (int nt = 0; nt < 2; nt++) {
                int n = wave*32 + nt*16 + l16;
                s16x8 bfr = *(const s16x8*)(&Bs[n*BK + so]);
                #pragma unroll
                for (int mt = 0; mt < 4; mt++)
                    acc[mt][nt] = __builtin_amdgcn_mfma_f32_16x16x32_bf16(af[mt], bfr, acc[mt][nt], 0, 0, 0);
            }
        }
        __syncthreads();
    }

    #pragma unroll
    for (int mt = 0; mt < 4; mt++) {
        #pragma unroll
        for (int r = 0; r < 4; r++) {
            int row = mt*16 + quad*4 + r;
            if (m0 + row < ce) {
                int t = tok[m0 + row];
                float s = twT[(size_t)e*N_TOK + t];
                #pragma unroll
                for (int nt = 0; nt < 2; nt++) {
                    int col = wave*32 + nt*16 + l16;
                    buf2[(size_t)(abase + row)*DIM + n0 + col] = acc[mt][nt][r] * s;
                }
            }
        }
    }
}

// ---------------- gather: out[t] = sum of buf2 rows for t's active experts ----------------
__global__ __launch_bounds__(128) void gather_kernel(void* ws, float* __restrict__ out)
{
    int t = blockIdx.x;
    int tid = threadIdx.x;
    const int* slot_of = ws_i32(ws, WS_SLOT);
    const float* buf2 = (const float*)((char*)ws + WS_BUF2);

    int d = tid * 4;
    float4 acc = {0.f, 0.f, 0.f, 0.f};
    #pragma unroll
    for (int e = 0; e < NE; e++) {
        int s = slot_of[e*N_TOK + t];      // wave-uniform per block
        if (s >= 0) {
            float4 v = *(const float4*)(buf2 + (size_t)s*DIM + d);
            acc.x += v.x; acc.y += v.y; acc.z += v.z; acc.w += v.w;
        }
    }
    *(float4*)(out + (size_t)t*DIM + d) = acc;
}

extern "C" void kernel_launch(void* const* d_in, const int* in_sizes, int n_in,
                              void* d_out, int out_size, void* d_ws, size_t ws_size,
                              hipStream_t stream)
{
    const float* x     = (const float*)d_in[0];
    const float* Wr    = (const float*)d_in[1];
    const float* br    = (const float*)d_in[2];
    const float* Wgate = (const float*)d_in[3];
    const float* bgate = (const float*)d_in[4];
    const float* W1    = (const float*)d_in[5];
    const float* W3    = (const float*)d_in[6];
    const float* W2    = (const float*)d_in[7];
    float* out = (float*)d_out;

    transpose_all_kernel<<<dim3(512), 1024, 0, stream>>>(W1, W3, W2, d_ws);
    routing_kernel<<<N_TOK/4, 256, 0, stream>>>(x, Wr, br, Wgate, bgate, d_ws);
    expert_scan_kernel<<<1, 1024, 0, stream>>>(d_ws);
    gemm1_fast<<<dim3(HID/BN, N_TOK/BM, NE), 256, 0, stream>>>(d_ws);
    gemm2_fast<<<dim3(DIM/BN, N_TOK/BM, NE), 256, 0, stream>>>(d_ws);
    gather_kernel<<<N_TOK, 128, 0, stream>>>(d_ws, out);
}

// Round 3
// 353.801 us; speedup vs baseline: 1.0131x; 1.0131x over previous
//
#include <hip/hip_runtime.h>
#include <math.h>

typedef unsigned short u16;
typedef unsigned int   u32;
typedef short s16x8 __attribute__((ext_vector_type(8)));
typedef float f32x4 __attribute__((ext_vector_type(4)));

#define N_TOK 2048
#define DIM   512
#define HID   2048
#define NE    16
#define NG    4
#define EPG   4
#define MAXT  2048

#define BM 64
#define BN 128
#define BK 64

// ---- workspace layout (bytes) ----
#define WS_CNT    0                              // 16 ints
#define WS_OFF    128                            // 17 ints
#define WS_TOKIDX 256                            // 16*2048 ints
#define WS_TW     (WS_TOKIDX + NE*MAXT*4)        // twT[e][t]: 16*2048 f32
#define WS_XB     (WS_TW + N_TOK*NE*4)           // 2048*512 u16 (bf16 x)
#define WS_HBUF   (WS_XB + (size_t)N_TOK*DIM*2)  // 8192*2048 u16
#define WS_W1T    (WS_HBUF + (size_t)8192*HID*2) // 16*2048*512 u16 (bf16 W1^T [e][n][k])
#define WS_W3T    (WS_W1T + (size_t)NE*HID*DIM*2)
#define WS_W2T    (WS_W3T + (size_t)NE*HID*DIM*2) // 16*512*2048 u16 (bf16 W2^T [e][n][k])
#define WS_SLOT   (WS_W2T + (size_t)NE*DIM*HID*2) // slot_of[e][t]: 16*2048 ints
// buf2 (8192*512 f32 = 16.8 MB) aliases W1T: W1T is dead once gemm1 completes,
// buf2 is written by gemm2 (after gemm1) and read by gather. Safe within one call
// and across graph replays (prep rewrites W1T first each call).
#define WS_BUF2   WS_W1T

__device__ __forceinline__ int* ws_i32(void* ws, size_t off) { return (int*)((char*)ws + off); }

__device__ __forceinline__ u16 f2b(float f) {   // fp32 -> bf16 RNE
    union { float f; u32 i; } v; v.f = f;
    u32 b = v.i;
    u32 r = b + 0x7FFFu + ((b >> 16) & 1u);
    return (u16)(r >> 16);
}

// async global->LDS, 16B/lane; LDS side is wave-uniform base + lane*16
__device__ __forceinline__ void gl_lds16(const u16* g, u16* l) {
    __builtin_amdgcn_global_load_lds((const __attribute__((address_space(1))) void*)g,
                                     (__attribute__((address_space(3))) void*)l, 16, 0, 0);
}

// ---------------- prep: routing (128 blocks) + W1/W3 convert-transpose (512 blocks) ----------------
// Heterogeneous 1024-thread blocks, role by blockIdx. Routing blocks have no barriers;
// transpose blocks keep the double-buffered pipeline (raw s_barrier, lgkmcnt-only drain).
// W2 transpose moved into the gemm1 dispatch (z==0) — it's only needed by gemm2.
__global__ __launch_bounds__(1024) void prep_kernel(
    const float* __restrict__ x, const float* __restrict__ Wr, const float* __restrict__ br,
    const float* __restrict__ Wgate, const float* __restrict__ bgate,
    const float* __restrict__ W1, const float* __restrict__ W3, void* ws)
{
    __shared__ u16 T[2][128*128];   // 2 x 32 KB (transpose path only)
    int tid = threadIdx.x;
    int bid = blockIdx.x;

    if (bid < 128) {
        // ---- routing: 16 waves, one token per wave ----
        int t = bid * 16 + (tid >> 6);
        int lane = tid & 63;

        float xl[8];
        {
            const float4* xr = (const float4*)(x + (size_t)t*DIM + lane*8);
            float4 a = xr[0], b = xr[1];
            xl[0]=a.x; xl[1]=a.y; xl[2]=a.z; xl[3]=a.w;
            xl[4]=b.x; xl[5]=b.y; xl[6]=b.z; xl[7]=b.w;
        }
        {
            union { u16 h[8]; uint4 q; } pk;
            #pragma unroll
            for (int i = 0; i < 8; i++) pk.h[i] = f2b(xl[i]);
            u16* xb = (u16*)((char*)ws + WS_XB);
            *(uint4*)(xb + (size_t)t*DIM + lane*8) = pk.q;
        }

        float gl[NG] = {0.f,0.f,0.f,0.f};
        float el[NE];
        #pragma unroll
        for (int e = 0; e < NE; e++) el[e] = 0.f;

        {
            const float4* Wr4 = (const float4*)Wr;
            #pragma unroll
            for (int c = 0; c < 8; c++) {
                float4 w = Wr4[lane*8 + c];
                gl[0] += xl[c]*w.x; gl[1] += xl[c]*w.y;
                gl[2] += xl[c]*w.z; gl[3] += xl[c]*w.w;
            }
        }
        {
            const float4* Wg4 = (const float4*)Wgate;
            #pragma unroll
            for (int g = 0; g < NG; g++) {
                #pragma unroll
                for (int c = 0; c < 8; c++) {
                    float4 w = Wg4[(size_t)g*DIM + lane*8 + c];
                    el[g*4+0] += xl[c]*w.x; el[g*4+1] += xl[c]*w.y;
                    el[g*4+2] += xl[c]*w.z; el[g*4+3] += xl[c]*w.w;
                }
            }
        }

        #pragma unroll
        for (int g = 0; g < NG; g++)
            #pragma unroll
            for (int s = 32; s; s >>= 1) gl[g] += __shfl_xor(gl[g], s);
        #pragma unroll
        for (int e = 0; e < NE; e++)
            #pragma unroll
            for (int s = 32; s; s >>= 1) el[e] += __shfl_xor(el[e], s);

        if (lane != 0) return;

        float gp[NG];
        float mx = -1e30f;
        #pragma unroll
        for (int g = 0; g < NG; g++) { gl[g] += br[g]; mx = fmaxf(mx, gl[g]); }
        float sum = 0.f;
        #pragma unroll
        for (int g = 0; g < NG; g++) { gp[g] = expf(gl[g] - mx); sum += gp[g]; }
        #pragma unroll
        for (int g = 0; g < NG; g++) gp[g] /= sum;

        int i0 = 0;
        #pragma unroll
        for (int g = 1; g < NG; g++) if (gp[g] > gp[i0]) i0 = g;
        int i1 = -1;
        #pragma unroll
        for (int g = 0; g < NG; g++) { if (g == i0) continue; if (i1 < 0 || gp[g] > gp[i1]) i1 = g; }

        bool act1 = (gp[i0] + gp[i1]) <= 0.9f;
        float mp0 = gp[i0], mp1 = act1 ? gp[i1] : 0.f;
        float inv = 1.f / (mp0 + mp1 + 1e-9f);
        float wg[NG] = {0.f,0.f,0.f,0.f};
        wg[i0] = mp0 * inv;
        wg[i1] = mp1 * inv;

        float tw[NE];
        #pragma unroll
        for (int g = 0; g < NG; g++) {
            float ep[EPG];
            float emx = -1e30f;
            #pragma unroll
            for (int j = 0; j < EPG; j++) {
                float v = el[g*4 + j] + bgate[g*4 + j];
                ep[j] = v; emx = fmaxf(emx, v);
            }
            float es = 0.f;
            #pragma unroll
            for (int j = 0; j < EPG; j++) { ep[j] = expf(ep[j] - emx); es += ep[j]; }
            #pragma unroll
            for (int j = 0; j < EPG; j++) ep[j] /= es;

            int j0 = 0;
            #pragma unroll
            for (int j = 1; j < EPG; j++) if (ep[j] > ep[j0]) j0 = j;
            int j1 = -1;
            #pragma unroll
            for (int j = 0; j < EPG; j++) { if (j == j0) continue; if (j1 < 0 || ep[j] > ep[j1]) j1 = j; }

            bool ea1 = (ep[j0] + ep[j1]) <= 0.9f;
            float e0 = ep[j0], e1 = ea1 ? ep[j1] : 0.f;
            float einv = 1.f / (e0 + e1 + 1e-9f);
            float we[EPG] = {0.f,0.f,0.f,0.f};
            we[j0] = e0 * einv;
            we[j1] = e1 * einv;
            #pragma unroll
            for (int j = 0; j < EPG; j++) tw[g*4 + j] = wg[g] * we[j] * 0.5f;   // SCALE = 1/sqrt(4)
        }

        float* twT = (float*)((char*)ws + WS_TW);
        #pragma unroll
        for (int e = 0; e < NE; e++) twT[(size_t)e*N_TOK + t] = tw[e];
        return;
    }

    // ---- W1/W3 convert+transpose: 512 blocks x 4 tiles of 128k x 128n ----
    int bx = bid - 128;
    int j = tid & 31, i0 = tid >> 5;     // j: n-micro (coalesced read), i0: k-micro
    int tg0 = bx * 4;                    // 2048 tiles (2 mats x 16 e x 64)

    const float* src; u16* dst; int k0, n0;
    float4 v0, v1, v2, v3;

    auto setup = [&](int tg) {
        int mat = tg >> 10, e = (tg >> 6) & 15, w = tg & 63;
        const float* s  = mat ? W3 : W1;
        u16* d = (u16*)((char*)ws + (mat ? WS_W3T : WS_W1T));
        k0 = (w & 3) << 7; n0 = (w >> 2) << 7;   // K=512: 4 k-tiles; N=2048: 16 n-tiles
        src = s + (size_t)e*DIM*HID + (size_t)(k0 + 4*i0)*HID + n0 + 4*j;
        dst = d + (size_t)e*HID*DIM;
    };
    auto issue_loads = [&]() {           // 4 x float4, 512B-contiguous segments
        v0 = *(const float4*)(src);
        v1 = *(const float4*)(src + HID);
        v2 = *(const float4*)(src + 2*HID);
        v3 = *(const float4*)(src + 3*HID);
    };

    setup(tg0);
    issue_loads();

    for (int it = 0; it < 4; ++it) {
        u16* dstc = dst; int k0c = k0, n0c = n0;
        u16* Tb = &T[it & 1][0];

        int pc = 4 * (i0 ^ ((j & 15) << 1));
        union { u16 h[4]; uint2 q; } p;
        p.h[0]=f2b(v0.x); p.h[1]=f2b(v1.x); p.h[2]=f2b(v2.x); p.h[3]=f2b(v3.x);
        *(uint2*)(&Tb[(4*j+0)*128 + pc]) = p.q;
        p.h[0]=f2b(v0.y); p.h[1]=f2b(v1.y); p.h[2]=f2b(v2.y); p.h[3]=f2b(v3.y);
        *(uint2*)(&Tb[(4*j+1)*128 + pc]) = p.q;
        p.h[0]=f2b(v0.z); p.h[1]=f2b(v1.z); p.h[2]=f2b(v2.z); p.h[3]=f2b(v3.z);
        *(uint2*)(&Tb[(4*j+2)*128 + pc]) = p.q;
        p.h[0]=f2b(v0.w); p.h[1]=f2b(v1.w); p.h[2]=f2b(v2.w); p.h[3]=f2b(v3.w);
        *(uint2*)(&Tb[(4*j+3)*128 + pc]) = p.q;

        if (it + 1 < 4) { setup(tg0 + it + 1); issue_loads(); }

        asm volatile("s_waitcnt lgkmcnt(0)" ::: "memory");
        __builtin_amdgcn_s_barrier();

        #pragma unroll
        for (int ph = 0; ph < 2; ++ph) {
            int idx = tid + ph*1024;
            int nr = idx >> 4, sg = idx & 15;
            int cp = (2*sg) ^ (((nr >> 2) & 15) << 1);
            *(s16x8*)(dstc + (size_t)(n0c+nr)*DIM + k0c + sg*8) = *(const s16x8*)(&Tb[nr*128 + 4*cp]);
        }
    }
}

// ---- expert lists + scan + slot map: 16 waves, two ballot passes, no atomics ----
__global__ __launch_bounds__(1024) void expert_scan_kernel(void* ws)
{
    int tid = threadIdx.x;
    int e = tid >> 6, lane = tid & 63;
    const float* twT = (const float*)((char*)ws + WS_TW) + (size_t)e*N_TOK;
    int* tok = ws_i32(ws, WS_TOKIDX) + e*MAXT;
    __shared__ int scnt[NE];
    __shared__ int soff[NE+1];

    float v[32];
    #pragma unroll
    for (int r = 0; r < 32; r++) v[r] = twT[r*64 + lane];

    unsigned long long lanemask = (1ull << lane) - 1ull;
    int base = 0;
    #pragma unroll
    for (int r = 0; r < 32; r++) {
        bool a = v[r] > 0.f;
        unsigned long long m = __ballot(a);
        if (a) tok[base + __popcll(m & lanemask)] = r*64 + lane;
        base += __popcll(m);
    }
    if (lane == 0) scnt[e] = base;
    __syncthreads();
    if (tid == 0) {
        int* cnt = ws_i32(ws, WS_CNT);
        int* off = ws_i32(ws, WS_OFF);
        int s = 0;
        for (int i = 0; i < NE; i++) { cnt[i] = scnt[i]; off[i] = s; soff[i] = s; s += scnt[i]; }
        off[NE] = s; soff[NE] = s;
    }
    __syncthreads();

    // pass 2: global slot per (e,t), -1 if inactive
    int* slot_of = ws_i32(ws, WS_SLOT) + e*N_TOK;
    int base2 = soff[e];
    #pragma unroll
    for (int r = 0; r < 32; r++) {
        bool a = v[r] > 0.f;
        unsigned long long m = __ballot(a);
        int pre = __popcll(m & lanemask);
        slot_of[r*64 + lane] = a ? (base2 + pre) : -1;
        base2 += __popcll(m);
    }
}

// ---------------- GEMM1 + W2 transpose (z==0): hbuf = bf16( silu(X W1) * (X W3) ) ----------------
// z==0 blocks convert+transpose W2 (needed only by gemm2, which is stream-ordered after
// this dispatch) — memory-streaming work hidden under gemm1's MFMA compute.
__global__ __launch_bounds__(256) void gemm1_fast(const float* __restrict__ W2, void* ws)
{
    __shared__ __align__(16) char smem[41216];
    int z = blockIdx.z;
    int tid = threadIdx.x;

    if (z == 0) {
        // ---- W2 [e][2048k][512n] fp32 -> W2T [e][512n][2048k] bf16, 2 tiles of 128x128 ----
        u16* T2 = (u16*)smem;                      // 32 KB
        u16* W2T = (u16*)((char*)ws + WS_W2T);
        int slot = blockIdx.x + 16*blockIdx.y;     // [0,512)
        int j = tid & 31, i = tid >> 5;            // j: n-micro, i: k-micro [0,8)
        #pragma unroll 1
        for (int tt = 0; tt < 2; ++tt) {
            int tile = slot + tt*512;              // [0,1024)
            int e = tile >> 6, w = tile & 63;
            int k0 = (w & 15) << 7, n0 = (w >> 4) << 7;   // K=2048: 16 k-tiles; N=512: 4 n-tiles
            const float* s = W2 + (size_t)e*HID*DIM + (size_t)k0*DIM + n0 + 4*j;
            if (tt) __syncthreads();
            #pragma unroll
            for (int c = 0; c < 4; ++c) {
                int kb = 4*i + 32*c;
                const float* base = s + (size_t)kb*DIM;
                float4 v0 = *(const float4*)(base);
                float4 v1 = *(const float4*)(base + DIM);
                float4 v2 = *(const float4*)(base + 2*DIM);
                float4 v3 = *(const float4*)(base + 3*DIM);
                int pc = 4 * ((i + 8*c) ^ ((j & 15) << 1));
                union { u16 h[4]; uint2 q; } p;
                p.h[0]=f2b(v0.x); p.h[1]=f2b(v1.x); p.h[2]=f2b(v2.x); p.h[3]=f2b(v3.x);
                *(uint2*)(&T2[(4*j+0)*128 + pc]) = p.q;
                p.h[0]=f2b(v0.y); p.h[1]=f2b(v1.y); p.h[2]=f2b(v2.y); p.h[3]=f2b(v3.y);
                *(uint2*)(&T2[(4*j+1)*128 + pc]) = p.q;
                p.h[0]=f2b(v0.z); p.h[1]=f2b(v1.z); p.h[2]=f2b(v2.z); p.h[3]=f2b(v3.z);
                *(uint2*)(&T2[(4*j+2)*128 + pc]) = p.q;
                p.h[0]=f2b(v0.w); p.h[1]=f2b(v1.w); p.h[2]=f2b(v2.w); p.h[3]=f2b(v3.w);
                *(uint2*)(&T2[(4*j+3)*128 + pc]) = p.q;
            }
            __syncthreads();
            u16* d = W2T + (size_t)e*DIM*HID;
            #pragma unroll
            for (int ph = 0; ph < 8; ++ph) {
                int idx = tid + ph*256;
                int nr = idx >> 4, sg = idx & 15;
                int cp = (2*sg) ^ (((nr >> 2) & 15) << 1);
                *(s16x8*)(d + (size_t)(n0+nr)*HID + k0 + sg*8) = *(const s16x8*)(&T2[nr*128 + 4*cp]);
            }
        }
        return;
    }

    int e  = z - 1;
    const int* cnt = ws_i32(ws, WS_CNT);
    int ce = cnt[e];
    int m0 = blockIdx.y * BM;
    if (m0 >= ce) return;
    int n0 = blockIdx.x * BN;

    const int* off = ws_i32(ws, WS_OFF);
    const int* tok = ws_i32(ws, WS_TOKIDX) + e*MAXT;
    const u16* xb  = (const u16*)((char*)ws + WS_XB);
    const u16* W1T = (const u16*)((char*)ws + WS_W1T) + (size_t)e*HID*DIM;  // [n][k]
    const u16* W3T = (const u16*)((char*)ws + WS_W3T) + (size_t)e*HID*DIM;
    u16* hbuf = (u16*)((char*)ws + WS_HBUF);
    int obase = off[e] + m0;

    u16* As  = (u16*)smem;            // 64*64*2   = 8 KB   swizzled [m][k]
    u16* Bs0 = (u16*)(smem + 8192);   // 128*64*2  = 16 KB  swizzled [n][k]
    u16* Bs1 = (u16*)(smem + 24576);  // 16 KB
    int* rowtok = (int*)(smem + 40960);

    if (tid < BM) {
        int m = m0 + tid;
        rowtok[tid] = tok[m < ce ? m : (ce - 1)];
    }
    __syncthreads();

    int wave = tid >> 6, lane = tid & 63;
    int quad = lane >> 4, l16 = lane & 15;
    int swz  = l16 & 7;
    int r8 = lane >> 3, sg = lane & 7;
    int swk = ((sg ^ r8) << 3);      // swizzle folded into global k-offset

    const u16* arow0 = xb + (size_t)rowtok[wave*16 + r8]*DIM + swk;
    const u16* arow1 = xb + (size_t)rowtok[wave*16 + 8 + r8]*DIM + swk;
    const u16* b1row[4]; const u16* b3row[4];
    #pragma unroll
    for (int i = 0; i < 4; i++) {
        size_t nr = (size_t)(n0 + wave*32 + i*8 + r8)*DIM + swk;
        b1row[i] = W1T + nr;
        b3row[i] = W3T + nr;
    }

    f32x4 acc1[4][2], acc3[4][2];
    #pragma unroll
    for (int mt = 0; mt < 4; mt++)
        #pragma unroll
        for (int nt = 0; nt < 2; nt++) {
            acc1[mt][nt] = (f32x4){0.f,0.f,0.f,0.f};
            acc3[mt][nt] = (f32x4){0.f,0.f,0.f,0.f};
        }

    for (int k0 = 0; k0 < DIM; k0 += BK) {
        gl_lds16(arow0 + k0, &As[(wave*16)*BK]);
        gl_lds16(arow1 + k0, &As[(wave*16 + 8)*BK]);
        #pragma unroll
        for (int i = 0; i < 4; i++) {
            gl_lds16(b1row[i] + k0, &Bs0[(wave*32 + i*8)*BK]);
            gl_lds16(b3row[i] + k0, &Bs1[(wave*32 + i*8)*BK]);
        }
        __syncthreads();

        #pragma unroll
        for (int kk = 0; kk < BK; kk += 32) {
            int jj = (kk >> 3) + quad;
            int so = ((jj ^ swz) << 3);
            s16x8 af[4];
            #pragma unroll
            for (int mt = 0; mt < 4; mt++)
                af[mt] = *(const s16x8*)(&As[(mt*16 + l16)*BK + so]);
            #pragma unroll
            for (int nt = 0; nt < 2; nt++) {
                int n = wave*32 + nt*16 + l16;
                s16x8 b1 = *(const s16x8*)(&Bs0[n*BK + so]);
                s16x8 b3 = *(const s16x8*)(&Bs1[n*BK + so]);
                #pragma unroll
                for (int mt = 0; mt < 4; mt++) {
                    acc1[mt][nt] = __builtin_amdgcn_mfma_f32_16x16x32_bf16(af[mt], b1, acc1[mt][nt], 0, 0, 0);
                    acc3[mt][nt] = __builtin_amdgcn_mfma_f32_16x16x32_bf16(af[mt], b3, acc3[mt][nt], 0, 0, 0);
                }
            }
        }
        __syncthreads();
    }

    #pragma unroll
    for (int mt = 0; mt < 4; mt++) {
        #pragma unroll
        for (int r = 0; r < 4; r++) {
            int row = mt*16 + quad*4 + r;
            if (m0 + row < ce) {
                #pragma unroll
                for (int nt = 0; nt < 2; nt++) {
                    float a = acc1[mt][nt][r];
                    float b = acc3[mt][nt][r];
                    float h = (a / (1.f + expf(-a))) * b;
                    int col = wave*32 + nt*16 + l16;
                    hbuf[(size_t)(obase + row)*HID + n0 + col] = f2b(h);
                }
            }
        }
    }
}

// ---------------- GEMM2: buf2 = tw * (h W2), plain stores (no atomics) ----------------
__global__ __launch_bounds__(256) void gemm2_fast(void* ws)
{
    int e  = blockIdx.z;
    const int* cnt = ws_i32(ws, WS_CNT);
    int ce = cnt[e];
    int m0 = blockIdx.y * BM;
    if (m0 >= ce) return;
    int n0 = blockIdx.x * BN;

    const int* off = ws_i32(ws, WS_OFF);
    const int* tok = ws_i32(ws, WS_TOKIDX) + e*MAXT;
    const float* twT = (const float*)((char*)ws + WS_TW);
    const u16* hbuf = (const u16*)((char*)ws + WS_HBUF);
    const u16* W2T = (const u16*)((char*)ws + WS_W2T) + (size_t)e*DIM*HID;  // [n=512][k=2048]
    float* buf2 = (float*)((char*)ws + WS_BUF2);
    int abase = off[e] + m0;
    int total = off[NE];

    __shared__ u16 As[BM*BK];
    __shared__ u16 Bs[BN*BK];

    int tid = threadIdx.x;
    int wave = tid >> 6, lane = tid & 63;
    int quad = lane >> 4, l16 = lane & 15;
    int swz  = l16 & 7;
    int r8 = lane >> 3, sg = lane & 7;
    int swk = ((sg ^ r8) << 3);

    int ar0 = abase + wave*16 + r8;      if (ar0 > total - 1) ar0 = total - 1;
    int ar1 = abase + wave*16 + 8 + r8;  if (ar1 > total - 1) ar1 = total - 1;
    const u16* arow0 = hbuf + (size_t)ar0*HID + swk;
    const u16* arow1 = hbuf + (size_t)ar1*HID + swk;
    const u16* brow[4];
    #pragma unroll
    for (int i = 0; i < 4; i++)
        brow[i] = W2T + (size_t)(n0 + wave*32 + i*8 + r8)*HID + swk;

    f32x4 acc[4][2];
    #pragma unroll
    for (int mt = 0; mt < 4; mt++)
        #pragma unroll
        for (int nt = 0; nt < 2; nt++) acc[mt][nt] = (f32x4){0.f,0.f,0.f,0.f};

    for (int k0 = 0; k0 < HID; k0 += BK) {
        gl_lds16(arow0 + k0, &As[(wave*16)*BK]);
        gl_lds16(arow1 + k0, &As[(wave*16 + 8)*BK]);
        #pragma unroll
        for (int i = 0; i < 4; i++)
            gl_lds16(brow[i] + k0, &Bs[(wave*32 + i*8)*BK]);
        __syncthreads();

        #pragma unroll
        for (int kk = 0; kk < BK; kk += 32) {
            int jj = (kk >> 3) + quad;
            int so = ((jj ^ swz) << 3);
            s16x8 af[4];
            #pragma unroll
            for (int mt = 0; mt < 4; mt++)
                af[mt] = *(const s16x8*)(&As[(mt*16 + l16)*BK + so]);
            #pragma unroll
            for (int nt = 0; nt < 2; nt++) {
                int n = wave*32 + nt*16 + l16;
                s16x8 bfr = *(const s16x8*)(&Bs[n*BK + so]);
                #pragma unroll
                for (int mt = 0; mt < 4; mt++)
                    acc[mt][nt] = __builtin_amdgcn_mfma_f32_16x16x32_bf16(af[mt], bfr, acc[mt][nt], 0, 0, 0);
            }
        }
        __syncthreads();
    }

    #pragma unroll
    for (int mt = 0; mt < 4; mt++) {
        #pragma unroll
        for (int r = 0; r < 4; r++) {
            int row = mt*16 + quad*4 + r;
            if (m0 + row < ce) {
                int t = tok[m0 + row];
                float s = twT[(size_t)e*N_TOK + t];
                #pragma unroll
                for (int nt = 0; nt < 2; nt++) {
                    int col = wave*32 + nt*16 + l16;
                    buf2[(size_t)(abase + row)*DIM + n0 + col] = acc[mt][nt][r] * s;
                }
            }
        }
    }
}

// ---------------- gather: out[t] = sum of buf2 rows for t's active experts ----------------
__global__ __launch_bounds__(128) void gather_kernel(void* ws, float* __restrict__ out)
{
    int t = blockIdx.x;
    int tid = threadIdx.x;
    const int* slot_of = ws_i32(ws, WS_SLOT);
    const float* buf2 = (const float*)((char*)ws + WS_BUF2);

    int d = tid * 4;
    float4 acc = {0.f, 0.f, 0.f, 0.f};
    #pragma unroll
    for (int e = 0; e < NE; e++) {
        int s = slot_of[e*N_TOK + t];      // wave-uniform per block
        if (s >= 0) {
            float4 v = *(const float4*)(buf2 + (size_t)s*DIM + d);
            acc.x += v.x; acc.y += v.y; acc.z += v.z; acc.w += v.w;
        }
    }
    *(float4*)(out + (size_t)t*DIM + d) = acc;
}

extern "C" void kernel_launch(void* const* d_in, const int* in_sizes, int n_in,
                              void* d_out, int out_size, void* d_ws, size_t ws_size,
                              hipStream_t stream)
{
    const float* x     = (const float*)d_in[0];
    const float* Wr    = (const float*)d_in[1];
    const float* br    = (const float*)d_in[2];
    const float* Wgate = (const float*)d_in[3];
    const float* bgate = (const float*)d_in[4];
    const float* W1    = (const float*)d_in[5];
    const float* W3    = (const float*)d_in[6];
    const float* W2    = (const float*)d_in[7];
    float* out = (float*)d_out;

    prep_kernel<<<640, 1024, 0, stream>>>(x, Wr, br, Wgate, bgate, W1, W3, d_ws);
    expert_scan_kernel<<<1, 1024, 0, stream>>>(d_ws);
    gemm1_fast<<<dim3(HID/BN, N_TOK/BM, NE + 1), 256, 0, stream>>>(W2, d_ws);
    gemm2_fast<<<dim3(DIM/BN, N_TOK/BM, NE), 256, 0, stream>>>(d_ws);
    gather_kernel<<<N_TOK, 128, 0, stream>>>(d_ws, out);
}

// Round 4
// 336.699 us; speedup vs baseline: 1.0646x; 1.0508x over previous
//
#include <hip/hip_runtime.h>
#include <math.h>

typedef unsigned short u16;
typedef unsigned int   u32;
typedef short s16x8 __attribute__((ext_vector_type(8)));
typedef float f32x4 __attribute__((ext_vector_type(4)));

#define N_TOK 2048
#define DIM   512
#define HID   2048
#define NE    16
#define NG    4
#define EPG   4
#define MAXT  2048

#define BM 64
#define BN 128
#define BK 64

// ---- workspace layout (bytes) ----
#define WS_CNT    0                              // 16 ints
#define WS_OFF    128                            // 17 ints
#define WS_TOKIDX 256                            // 16*2048 ints
#define WS_TW     (WS_TOKIDX + NE*MAXT*4)        // twT[e][t]: 16*2048 f32
#define WS_XB     (WS_TW + N_TOK*NE*4)           // 2048*512 u16 (bf16 x)
#define WS_HBUF   (WS_XB + (size_t)N_TOK*DIM*2)  // 8192*2048 u16
#define WS_W1T    (WS_HBUF + (size_t)8192*HID*2) // 16*2048*512 u16 (bf16 W1^T [e][n][k])
#define WS_W3T    (WS_W1T + (size_t)NE*HID*DIM*2)
#define WS_W2T    (WS_W3T + (size_t)NE*HID*DIM*2) // 16*512*2048 u16 (bf16 W2^T [e][n][k])
#define WS_SLOT   (WS_W2T + (size_t)NE*DIM*HID*2) // slot_of[e][t]: 16*2048 ints
// buf2 (8192*512 f32 = 16.8 MB) aliases W1T: W1T is dead once gemm1 completes,
// buf2 is written by gemm2 (after gemm1) and read by gather. Safe within one call
// and across graph replays (prep rewrites W1T first each call).
#define WS_BUF2   WS_W1T

__device__ __forceinline__ int* ws_i32(void* ws, size_t off) { return (int*)((char*)ws + off); }

__device__ __forceinline__ u16 f2b(float f) {   // fp32 -> bf16 RNE
    union { float f; u32 i; } v; v.f = f;
    u32 b = v.i;
    u32 r = b + 0x7FFFu + ((b >> 16) & 1u);
    return (u16)(r >> 16);
}

// async global->LDS, 16B/lane; LDS side is wave-uniform base + lane*16
__device__ __forceinline__ void gl_lds16(const u16* g, u16* l) {
    __builtin_amdgcn_global_load_lds((const __attribute__((address_space(1))) void*)g,
                                     (__attribute__((address_space(3))) void*)l, 16, 0, 0);
}

// ---------------- prep: routing (128 blocks) + W1/W3 convert-transpose (512 blocks) ----------------
// Heterogeneous 1024-thread blocks, role by blockIdx. Routing blocks have no barriers;
// transpose blocks keep the double-buffered pipeline (raw s_barrier, lgkmcnt-only drain).
// W2 transpose lives in the gemm1 dispatch at z==NE (launches LAST, overlaps gemm1 tail).
__global__ __launch_bounds__(1024) void prep_kernel(
    const float* __restrict__ x, const float* __restrict__ Wr, const float* __restrict__ br,
    const float* __restrict__ Wgate, const float* __restrict__ bgate,
    const float* __restrict__ W1, const float* __restrict__ W3, void* ws)
{
    __shared__ u16 T[2][128*128];   // 2 x 32 KB (transpose path only)
    int tid = threadIdx.x;
    int bid = blockIdx.x;

    if (bid < 128) {
        // ---- routing: 16 waves, one token per wave ----
        int t = bid * 16 + (tid >> 6);
        int lane = tid & 63;

        float xl[8];
        {
            const float4* xr = (const float4*)(x + (size_t)t*DIM + lane*8);
            float4 a = xr[0], b = xr[1];
            xl[0]=a.x; xl[1]=a.y; xl[2]=a.z; xl[3]=a.w;
            xl[4]=b.x; xl[5]=b.y; xl[6]=b.z; xl[7]=b.w;
        }
        {
            union { u16 h[8]; uint4 q; } pk;
            #pragma unroll
            for (int i = 0; i < 8; i++) pk.h[i] = f2b(xl[i]);
            u16* xb = (u16*)((char*)ws + WS_XB);
            *(uint4*)(xb + (size_t)t*DIM + lane*8) = pk.q;
        }

        float gl[NG] = {0.f,0.f,0.f,0.f};
        float el[NE];
        #pragma unroll
        for (int e = 0; e < NE; e++) el[e] = 0.f;

        {
            const float4* Wr4 = (const float4*)Wr;
            #pragma unroll
            for (int c = 0; c < 8; c++) {
                float4 w = Wr4[lane*8 + c];
                gl[0] += xl[c]*w.x; gl[1] += xl[c]*w.y;
                gl[2] += xl[c]*w.z; gl[3] += xl[c]*w.w;
            }
        }
        {
            const float4* Wg4 = (const float4*)Wgate;
            #pragma unroll
            for (int g = 0; g < NG; g++) {
                #pragma unroll
                for (int c = 0; c < 8; c++) {
                    float4 w = Wg4[(size_t)g*DIM + lane*8 + c];
                    el[g*4+0] += xl[c]*w.x; el[g*4+1] += xl[c]*w.y;
                    el[g*4+2] += xl[c]*w.z; el[g*4+3] += xl[c]*w.w;
                }
            }
        }

        #pragma unroll
        for (int g = 0; g < NG; g++)
            #pragma unroll
            for (int s = 32; s; s >>= 1) gl[g] += __shfl_xor(gl[g], s);
        #pragma unroll
        for (int e = 0; e < NE; e++)
            #pragma unroll
            for (int s = 32; s; s >>= 1) el[e] += __shfl_xor(el[e], s);

        if (lane != 0) return;

        float gp[NG];
        float mx = -1e30f;
        #pragma unroll
        for (int g = 0; g < NG; g++) { gl[g] += br[g]; mx = fmaxf(mx, gl[g]); }
        float sum = 0.f;
        #pragma unroll
        for (int g = 0; g < NG; g++) { gp[g] = expf(gl[g] - mx); sum += gp[g]; }
        #pragma unroll
        for (int g = 0; g < NG; g++) gp[g] /= sum;

        int i0 = 0;
        #pragma unroll
        for (int g = 1; g < NG; g++) if (gp[g] > gp[i0]) i0 = g;
        int i1 = -1;
        #pragma unroll
        for (int g = 0; g < NG; g++) { if (g == i0) continue; if (i1 < 0 || gp[g] > gp[i1]) i1 = g; }

        bool act1 = (gp[i0] + gp[i1]) <= 0.9f;
        float mp0 = gp[i0], mp1 = act1 ? gp[i1] : 0.f;
        float inv = 1.f / (mp0 + mp1 + 1e-9f);
        float wg[NG] = {0.f,0.f,0.f,0.f};
        wg[i0] = mp0 * inv;
        wg[i1] = mp1 * inv;

        float tw[NE];
        #pragma unroll
        for (int g = 0; g < NG; g++) {
            float ep[EPG];
            float emx = -1e30f;
            #pragma unroll
            for (int j = 0; j < EPG; j++) {
                float v = el[g*4 + j] + bgate[g*4 + j];
                ep[j] = v; emx = fmaxf(emx, v);
            }
            float es = 0.f;
            #pragma unroll
            for (int j = 0; j < EPG; j++) { ep[j] = expf(ep[j] - emx); es += ep[j]; }
            #pragma unroll
            for (int j = 0; j < EPG; j++) ep[j] /= es;

            int j0 = 0;
            #pragma unroll
            for (int j = 1; j < EPG; j++) if (ep[j] > ep[j0]) j0 = j;
            int j1 = -1;
            #pragma unroll
            for (int j = 0; j < EPG; j++) { if (j == j0) continue; if (j1 < 0 || ep[j] > ep[j1]) j1 = j; }

            bool ea1 = (ep[j0] + ep[j1]) <= 0.9f;
            float e0 = ep[j0], e1 = ea1 ? ep[j1] : 0.f;
            float einv = 1.f / (e0 + e1 + 1e-9f);
            float we[EPG] = {0.f,0.f,0.f,0.f};
            we[j0] = e0 * einv;
            we[j1] = e1 * einv;
            #pragma unroll
            for (int j = 0; j < EPG; j++) tw[g*4 + j] = wg[g] * we[j] * 0.5f;   // SCALE = 1/sqrt(4)
        }

        float* twT = (float*)((char*)ws + WS_TW);
        #pragma unroll
        for (int e = 0; e < NE; e++) twT[(size_t)e*N_TOK + t] = tw[e];
        return;
    }

    // ---- W1/W3 convert+transpose: 512 blocks x 4 tiles of 128k x 128n ----
    int bx = bid - 128;
    int j = tid & 31, i0 = tid >> 5;     // j: n-micro (coalesced read), i0: k-micro
    int tg0 = bx * 4;                    // 2048 tiles (2 mats x 16 e x 64)

    const float* src; u16* dst; int k0, n0;
    float4 v0, v1, v2, v3;

    auto setup = [&](int tg) {
        int mat = tg >> 10, e = (tg >> 6) & 15, w = tg & 63;
        const float* s  = mat ? W3 : W1;
        u16* d = (u16*)((char*)ws + (mat ? WS_W3T : WS_W1T));
        k0 = (w & 3) << 7; n0 = (w >> 2) << 7;   // K=512: 4 k-tiles; N=2048: 16 n-tiles
        src = s + (size_t)e*DIM*HID + (size_t)(k0 + 4*i0)*HID + n0 + 4*j;
        dst = d + (size_t)e*HID*DIM;
    };
    auto issue_loads = [&]() {           // 4 x float4, 512B-contiguous segments
        v0 = *(const float4*)(src);
        v1 = *(const float4*)(src + HID);
        v2 = *(const float4*)(src + 2*HID);
        v3 = *(const float4*)(src + 3*HID);
    };

    setup(tg0);
    issue_loads();

    for (int it = 0; it < 4; ++it) {
        u16* dstc = dst; int k0c = k0, n0c = n0;
        u16* Tb = &T[it & 1][0];

        int pc = 4 * (i0 ^ ((j & 15) << 1));
        union { u16 h[4]; uint2 q; } p;
        p.h[0]=f2b(v0.x); p.h[1]=f2b(v1.x); p.h[2]=f2b(v2.x); p.h[3]=f2b(v3.x);
        *(uint2*)(&Tb[(4*j+0)*128 + pc]) = p.q;
        p.h[0]=f2b(v0.y); p.h[1]=f2b(v1.y); p.h[2]=f2b(v2.y); p.h[3]=f2b(v3.y);
        *(uint2*)(&Tb[(4*j+1)*128 + pc]) = p.q;
        p.h[0]=f2b(v0.z); p.h[1]=f2b(v1.z); p.h[2]=f2b(v2.z); p.h[3]=f2b(v3.z);
        *(uint2*)(&Tb[(4*j+2)*128 + pc]) = p.q;
        p.h[0]=f2b(v0.w); p.h[1]=f2b(v1.w); p.h[2]=f2b(v2.w); p.h[3]=f2b(v3.w);
        *(uint2*)(&Tb[(4*j+3)*128 + pc]) = p.q;

        if (it + 1 < 4) { setup(tg0 + it + 1); issue_loads(); }

        asm volatile("s_waitcnt lgkmcnt(0)" ::: "memory");
        __builtin_amdgcn_s_barrier();

        #pragma unroll
        for (int ph = 0; ph < 2; ++ph) {
            int idx = tid + ph*1024;
            int nr = idx >> 4, sg = idx & 15;
            int cp = (2*sg) ^ (((nr >> 2) & 15) << 1);
            *(s16x8*)(dstc + (size_t)(n0c+nr)*DIM + k0c + sg*8) = *(const s16x8*)(&Tb[nr*128 + 4*cp]);
        }
    }
}

// ---- expert lists + scan + slot map: 16 waves, two ballot passes, no atomics ----
__global__ __launch_bounds__(1024) void expert_scan_kernel(void* ws)
{
    int tid = threadIdx.x;
    int e = tid >> 6, lane = tid & 63;
    const float* twT = (const float*)((char*)ws + WS_TW) + (size_t)e*N_TOK;
    int* tok = ws_i32(ws, WS_TOKIDX) + e*MAXT;
    __shared__ int scnt[NE];
    __shared__ int soff[NE+1];

    float v[32];
    #pragma unroll
    for (int r = 0; r < 32; r++) v[r] = twT[r*64 + lane];

    unsigned long long lanemask = (1ull << lane) - 1ull;
    int base = 0;
    #pragma unroll
    for (int r = 0; r < 32; r++) {
        bool a = v[r] > 0.f;
        unsigned long long m = __ballot(a);
        if (a) tok[base + __popcll(m & lanemask)] = r*64 + lane;
        base += __popcll(m);
    }
    if (lane == 0) scnt[e] = base;
    __syncthreads();
    if (tid == 0) {
        int* cnt = ws_i32(ws, WS_CNT);
        int* off = ws_i32(ws, WS_OFF);
        int s = 0;
        for (int i = 0; i < NE; i++) { cnt[i] = scnt[i]; off[i] = s; soff[i] = s; s += scnt[i]; }
        off[NE] = s; soff[NE] = s;
    }
    __syncthreads();

    // pass 2: global slot per (e,t), -1 if inactive
    int* slot_of = ws_i32(ws, WS_SLOT) + e*N_TOK;
    int base2 = soff[e];
    #pragma unroll
    for (int r = 0; r < 32; r++) {
        bool a = v[r] > 0.f;
        unsigned long long m = __ballot(a);
        int pre = __popcll(m & lanemask);
        slot_of[r*64 + lane] = a ? (base2 + pre) : -1;
        base2 += __popcll(m);
    }
}

// ---------------- GEMM1 + W2 transpose (z==NE, launches LAST): hbuf = bf16( silu(X W1) * (X W3) ) ----------------
// z==NE blocks convert+transpose W2 (needed only by gemm2, stream-ordered after this
// dispatch). z-slowest dispatch order means these stream AFTER the GEMM blocks start,
// overlapping gemm1's tail instead of serializing at its head (round-3 lesson).
// LDS carved from one 40960-B block => exactly 4 blocks/CU (was 41472 -> 3/CU).
__global__ __launch_bounds__(256) void gemm1_fast(const float* __restrict__ W2, void* ws)
{
    __shared__ __align__(16) u16 SM[20480];   // 40960 B exactly
    int z = blockIdx.z;
    int tid = threadIdx.x;

    if (z == NE) {
        // ---- W2 [e][2048k][512n] fp32 -> W2T [e][512n][2048k] bf16, 2 tiles of 128x128 ----
        u16* T2 = SM;                              // 32 KB of the 40 KB block
        u16* W2T = (u16*)((char*)ws + WS_W2T);
        int slot = blockIdx.x + 16*blockIdx.y;     // [0,512)
        int j = tid & 31, i = tid >> 5;            // j: n-micro, i: k-micro [0,8)
        #pragma unroll 1
        for (int tt = 0; tt < 2; ++tt) {
            int tile = slot + tt*512;              // [0,1024)
            int e = tile >> 6, w = tile & 63;
            int k0 = (w & 15) << 7, n0 = (w >> 4) << 7;   // K=2048: 16 k-tiles; N=512: 4 n-tiles
            const float* s = W2 + (size_t)e*HID*DIM + (size_t)k0*DIM + n0 + 4*j;
            if (tt) __syncthreads();
            #pragma unroll
            for (int c = 0; c < 4; ++c) {
                int kb = 4*i + 32*c;
                const float* base = s + (size_t)kb*DIM;
                float4 v0 = *(const float4*)(base);
                float4 v1 = *(const float4*)(base + DIM);
                float4 v2 = *(const float4*)(base + 2*DIM);
                float4 v3 = *(const float4*)(base + 3*DIM);
                int pc = 4 * ((i + 8*c) ^ ((j & 15) << 1));
                union { u16 h[4]; uint2 q; } p;
                p.h[0]=f2b(v0.x); p.h[1]=f2b(v1.x); p.h[2]=f2b(v2.x); p.h[3]=f2b(v3.x);
                *(uint2*)(&T2[(4*j+0)*128 + pc]) = p.q;
                p.h[0]=f2b(v0.y); p.h[1]=f2b(v1.y); p.h[2]=f2b(v2.y); p.h[3]=f2b(v3.y);
                *(uint2*)(&T2[(4*j+1)*128 + pc]) = p.q;
                p.h[0]=f2b(v0.z); p.h[1]=f2b(v1.z); p.h[2]=f2b(v2.z); p.h[3]=f2b(v3.z);
                *(uint2*)(&T2[(4*j+2)*128 + pc]) = p.q;
                p.h[0]=f2b(v0.w); p.h[1]=f2b(v1.w); p.h[2]=f2b(v2.w); p.h[3]=f2b(v3.w);
                *(uint2*)(&T2[(4*j+3)*128 + pc]) = p.q;
            }
            __syncthreads();
            u16* d = W2T + (size_t)e*DIM*HID;
            #pragma unroll
            for (int ph = 0; ph < 8; ++ph) {
                int idx = tid + ph*256;
                int nr = idx >> 4, sg = idx & 15;
                int cp = (2*sg) ^ (((nr >> 2) & 15) << 1);
                *(s16x8*)(d + (size_t)(n0+nr)*HID + k0 + sg*8) = *(const s16x8*)(&T2[nr*128 + 4*cp]);
            }
        }
        return;
    }

    int e  = z;
    const int* cnt = ws_i32(ws, WS_CNT);
    int ce = cnt[e];
    int m0 = blockIdx.y * BM;
    if (m0 >= ce) return;
    int n0 = blockIdx.x * BN;

    const int* off = ws_i32(ws, WS_OFF);
    const int* tok = ws_i32(ws, WS_TOKIDX) + e*MAXT;
    const u16* xb  = (const u16*)((char*)ws + WS_XB);
    const u16* W1T = (const u16*)((char*)ws + WS_W1T) + (size_t)e*HID*DIM;  // [n][k]
    const u16* W3T = (const u16*)((char*)ws + WS_W3T) + (size_t)e*HID*DIM;
    u16* hbuf = (u16*)((char*)ws + WS_HBUF);
    int obase = off[e] + m0;

    u16* As  = SM;           // 8 KB   swizzled [m][k]
    u16* Bs0 = SM + 4096;    // 16 KB  swizzled [n][k]
    u16* Bs1 = SM + 12288;   // 16 KB

    int wave = tid >> 6, lane = tid & 63;
    int quad = lane >> 4, l16 = lane & 15;
    int swz  = l16 & 7;
    int r8 = lane >> 3, sg = lane & 7;
    int swk = ((sg ^ r8) << 3);      // swizzle folded into global k-offset

    // token rows direct from global (L2-hit), clamped to ce-1 — no LDS round trip
    int m_a0 = m0 + wave*16 + r8;     if (m_a0 >= ce) m_a0 = ce - 1;
    int m_a1 = m0 + wave*16 + 8 + r8; if (m_a1 >= ce) m_a1 = ce - 1;
    const u16* arow0 = xb + (size_t)tok[m_a0]*DIM + swk;
    const u16* arow1 = xb + (size_t)tok[m_a1]*DIM + swk;
    const u16* b1row[4]; const u16* b3row[4];
    #pragma unroll
    for (int i = 0; i < 4; i++) {
        size_t nr = (size_t)(n0 + wave*32 + i*8 + r8)*DIM + swk;
        b1row[i] = W1T + nr;
        b3row[i] = W3T + nr;
    }

    f32x4 acc1[4][2], acc3[4][2];
    #pragma unroll
    for (int mt = 0; mt < 4; mt++)
        #pragma unroll
        for (int nt = 0; nt < 2; nt++) {
            acc1[mt][nt] = (f32x4){0.f,0.f,0.f,0.f};
            acc3[mt][nt] = (f32x4){0.f,0.f,0.f,0.f};
        }

    for (int k0 = 0; k0 < DIM; k0 += BK) {
        gl_lds16(arow0 + k0, &As[(wave*16)*BK]);
        gl_lds16(arow1 + k0, &As[(wave*16 + 8)*BK]);
        #pragma unroll
        for (int i = 0; i < 4; i++) {
            gl_lds16(b1row[i] + k0, &Bs0[(wave*32 + i*8)*BK]);
            gl_lds16(b3row[i] + k0, &Bs1[(wave*32 + i*8)*BK]);
        }
        __syncthreads();

        #pragma unroll
        for (int kk = 0; kk < BK; kk += 32) {
            int jj = (kk >> 3) + quad;
            int so = ((jj ^ swz) << 3);
            s16x8 af[4];
            #pragma unroll
            for (int mt = 0; mt < 4; mt++)
                af[mt] = *(const s16x8*)(&As[(mt*16 + l16)*BK + so]);
            #pragma unroll
            for (int nt = 0; nt < 2; nt++) {
                int n = wave*32 + nt*16 + l16;
                s16x8 b1 = *(const s16x8*)(&Bs0[n*BK + so]);
                s16x8 b3 = *(const s16x8*)(&Bs1[n*BK + so]);
                #pragma unroll
                for (int mt = 0; mt < 4; mt++) {
                    acc1[mt][nt] = __builtin_amdgcn_mfma_f32_16x16x32_bf16(af[mt], b1, acc1[mt][nt], 0, 0, 0);
                    acc3[mt][nt] = __builtin_amdgcn_mfma_f32_16x16x32_bf16(af[mt], b3, acc3[mt][nt], 0, 0, 0);
                }
            }
        }
        __syncthreads();
    }

    #pragma unroll
    for (int mt = 0; mt < 4; mt++) {
        #pragma unroll
        for (int r = 0; r < 4; r++) {
            int row = mt*16 + quad*4 + r;
            if (m0 + row < ce) {
                #pragma unroll
                for (int nt = 0; nt < 2; nt++) {
                    float a = acc1[mt][nt][r];
                    float b = acc3[mt][nt][r];
                    float h = (a / (1.f + expf(-a))) * b;
                    int col = wave*32 + nt*16 + l16;
                    hbuf[(size_t)(obase + row)*HID + n0 + col] = f2b(h);
                }
            }
        }
    }
}

// ---------------- GEMM2: buf2 = tw * (h W2), plain stores (no atomics) ----------------
__global__ __launch_bounds__(256) void gemm2_fast(void* ws)
{
    int e  = blockIdx.z;
    const int* cnt = ws_i32(ws, WS_CNT);
    int ce = cnt[e];
    int m0 = blockIdx.y * BM;
    if (m0 >= ce) return;
    int n0 = blockIdx.x * BN;

    const int* off = ws_i32(ws, WS_OFF);
    const int* tok = ws_i32(ws, WS_TOKIDX) + e*MAXT;
    const float* twT = (const float*)((char*)ws + WS_TW);
    const u16* hbuf = (const u16*)((char*)ws + WS_HBUF);
    const u16* W2T = (const u16*)((char*)ws + WS_W2T) + (size_t)e*DIM*HID;  // [n=512][k=2048]
    float* buf2 = (float*)((char*)ws + WS_BUF2);
    int abase = off[e] + m0;
    int total = off[NE];

    __shared__ u16 As[BM*BK];
    __shared__ u16 Bs[BN*BK];

    int tid = threadIdx.x;
    int wave = tid >> 6, lane = tid & 63;
    int quad = lane >> 4, l16 = lane & 15;
    int swz  = l16 & 7;
    int r8 = lane >> 3, sg = lane & 7;
    int swk = ((sg ^ r8) << 3);

    int ar0 = abase + wave*16 + r8;      if (ar0 > total - 1) ar0 = total - 1;
    int ar1 = abase + wave*16 + 8 + r8;  if (ar1 > total - 1) ar1 = total - 1;
    const u16* arow0 = hbuf + (size_t)ar0*HID + swk;
    const u16* arow1 = hbuf + (size_t)ar1*HID + swk;
    const u16* brow[4];
    #pragma unroll
    for (int i = 0; i < 4; i++)
        brow[i] = W2T + (size_t)(n0 + wave*32 + i*8 + r8)*HID + swk;

    f32x4 acc[4][2];
    #pragma unroll
    for (int mt = 0; mt < 4; mt++)
        #pragma unroll
        for (int nt = 0; nt < 2; nt++) acc[mt][nt] = (f32x4){0.f,0.f,0.f,0.f};

    for (int k0 = 0; k0 < HID; k0 += BK) {
        gl_lds16(arow0 + k0, &As[(wave*16)*BK]);
        gl_lds16(arow1 + k0, &As[(wave*16 + 8)*BK]);
        #pragma unroll
        for (int i = 0; i < 4; i++)
            gl_lds16(brow[i] + k0, &Bs[(wave*32 + i*8)*BK]);
        __syncthreads();

        #pragma unroll
        for (int kk = 0; kk < BK; kk += 32) {
            int jj = (kk >> 3) + quad;
            int so = ((jj ^ swz) << 3);
            s16x8 af[4];
            #pragma unroll
            for (int mt = 0; mt < 4; mt++)
                af[mt] = *(const s16x8*)(&As[(mt*16 + l16)*BK + so]);
            #pragma unroll
            for (int nt = 0; nt < 2; nt++) {
                int n = wave*32 + nt*16 + l16;
                s16x8 bfr = *(const s16x8*)(&Bs[n*BK + so]);
                #pragma unroll
                for (int mt = 0; mt < 4; mt++)
                    acc[mt][nt] = __builtin_amdgcn_mfma_f32_16x16x32_bf16(af[mt], bfr, acc[mt][nt], 0, 0, 0);
            }
        }
        __syncthreads();
    }

    #pragma unroll
    for (int mt = 0; mt < 4; mt++) {
        #pragma unroll
        for (int r = 0; r < 4; r++) {
            int row = mt*16 + quad*4 + r;
            if (m0 + row < ce) {
                int t = tok[m0 + row];
                float s = twT[(size_t)e*N_TOK + t];
                #pragma unroll
                for (int nt = 0; nt < 2; nt++) {
                    int col = wave*32 + nt*16 + l16;
                    buf2[(size_t)(abase + row)*DIM + n0 + col] = acc[mt][nt][r] * s;
                }
            }
        }
    }
}

// ---------------- gather: out[t] = sum of buf2 rows for t's active experts ----------------
__global__ __launch_bounds__(128) void gather_kernel(void* ws, float* __restrict__ out)
{
    int t = blockIdx.x;
    int tid = threadIdx.x;
    const int* slot_of = ws_i32(ws, WS_SLOT);
    const float* buf2 = (const float*)((char*)ws + WS_BUF2);

    int d = tid * 4;
    float4 acc = {0.f, 0.f, 0.f, 0.f};
    #pragma unroll
    for (int e = 0; e < NE; e++) {
        int s = slot_of[e*N_TOK + t];      // wave-uniform per block
        if (s >= 0) {
            float4 v = *(const float4*)(buf2 + (size_t)s*DIM + d);
            acc.x += v.x; acc.y += v.y; acc.z += v.z; acc.w += v.w;
        }
    }
    *(float4*)(out + (size_t)t*DIM + d) = acc;
}

extern "C" void kernel_launch(void* const* d_in, const int* in_sizes, int n_in,
                              void* d_out, int out_size, void* d_ws, size_t ws_size,
                              hipStream_t stream)
{
    const float* x     = (const float*)d_in[0];
    const float* Wr    = (const float*)d_in[1];
    const float* br    = (const float*)d_in[2];
    const float* Wgate = (const float*)d_in[3];
    const float* bgate = (const float*)d_in[4];
    const float* W1    = (const float*)d_in[5];
    const float* W3    = (const float*)d_in[6];
    const float* W2    = (const float*)d_in[7];
    float* out = (float*)d_out;

    prep_kernel<<<640, 1024, 0, stream>>>(x, Wr, br, Wgate, bgate, W1, W3, d_ws);
    expert_scan_kernel<<<1, 1024, 0, stream>>>(d_ws);
    gemm1_fast<<<dim3(HID/BN, N_TOK/BM, NE + 1), 256, 0, stream>>>(W2, d_ws);
    gemm2_fast<<<dim3(DIM/BN, N_TOK/BM, NE), 256, 0, stream>>>(d_ws);
    gather_kernel<<<N_TOK, 128, 0, stream>>>(d_ws, out);
}

// Round 5
// 326.197 us; speedup vs baseline: 1.0988x; 1.0322x over previous
//
#include <hip/hip_runtime.h>
#include <math.h>

typedef unsigned short u16;
typedef unsigned int   u32;
typedef short s16x8 __attribute__((ext_vector_type(8)));
typedef float f32x4 __attribute__((ext_vector_type(4)));

#define N_TOK 2048
#define DIM   512
#define HID   2048
#define NE    16
#define NG    4
#define EPG   4
#define MAXT  2048

#define BM 64
#define BN 128
#define BK 64

// ---- workspace layout (bytes) ----
#define WS_CNT    0                              // 16 ints
#define WS_OFF    128                            // 17 ints
#define WS_TOKIDX 256                            // 16*2048 ints
#define WS_TW     (WS_TOKIDX + NE*MAXT*4)        // twT[e][t]: 16*2048 f32
#define WS_XB     (WS_TW + N_TOK*NE*4)           // 2048*512 u16 (bf16 x)
#define WS_HBUF   (WS_XB + (size_t)N_TOK*DIM*2)  // 8192*2048 u16
#define WS_W1T    (WS_HBUF + (size_t)8192*HID*2) // 16*2048*512 u16 (bf16 W1^T [e][n][k])
#define WS_W3T    (WS_W1T + (size_t)NE*HID*DIM*2)
#define WS_W2T    (WS_W3T + (size_t)NE*HID*DIM*2) // 16*512*2048 u16 (bf16 W2^T [e][n][k])
#define WS_SLOT   (WS_W2T + (size_t)NE*DIM*HID*2) // slot_of[e][t]: 16*2048 ints
// buf2 (8192*512 f32 = 16.8 MB) aliases W1T: W1T is dead once gemm1 completes,
// buf2 is written by gemm2 (after gemm1) and read by gather. Safe within one call
// and across graph replays (prep rewrites W1T first each call).
#define WS_BUF2   WS_W1T

__device__ __forceinline__ int* ws_i32(void* ws, size_t off) { return (int*)((char*)ws + off); }

__device__ __forceinline__ u16 f2b(float f) {   // fp32 -> bf16 RNE
    union { float f; u32 i; } v; v.f = f;
    u32 b = v.i;
    u32 r = b + 0x7FFFu + ((b >> 16) & 1u);
    return (u16)(r >> 16);
}

// async global->LDS, 16B/lane; LDS side is wave-uniform base + lane*16
__device__ __forceinline__ void gl_lds16(const u16* g, u16* l) {
    __builtin_amdgcn_global_load_lds((const __attribute__((address_space(1))) void*)g,
                                     (__attribute__((address_space(3))) void*)l, 16, 0, 0);
}

// ---------------- prep: routing (128 blocks) + W1/W3 convert-transpose (512 blocks) ----------------
__global__ __launch_bounds__(1024) void prep_kernel(
    const float* __restrict__ x, const float* __restrict__ Wr, const float* __restrict__ br,
    const float* __restrict__ Wgate, const float* __restrict__ bgate,
    const float* __restrict__ W1, const float* __restrict__ W3, void* ws)
{
    __shared__ u16 T[2][128*128];   // 2 x 32 KB (transpose path only)
    int tid = threadIdx.x;
    int bid = blockIdx.x;

    if (bid < 128) {
        // ---- routing: 16 waves, one token per wave ----
        int t = bid * 16 + (tid >> 6);
        int lane = tid & 63;

        float xl[8];
        {
            const float4* xr = (const float4*)(x + (size_t)t*DIM + lane*8);
            float4 a = xr[0], b = xr[1];
            xl[0]=a.x; xl[1]=a.y; xl[2]=a.z; xl[3]=a.w;
            xl[4]=b.x; xl[5]=b.y; xl[6]=b.z; xl[7]=b.w;
        }
        {
            union { u16 h[8]; uint4 q; } pk;
            #pragma unroll
            for (int i = 0; i < 8; i++) pk.h[i] = f2b(xl[i]);
            u16* xb = (u16*)((char*)ws + WS_XB);
            *(uint4*)(xb + (size_t)t*DIM + lane*8) = pk.q;
        }

        float gl[NG] = {0.f,0.f,0.f,0.f};
        float el[NE];
        #pragma unroll
        for (int e = 0; e < NE; e++) el[e] = 0.f;

        {
            const float4* Wr4 = (const float4*)Wr;
            #pragma unroll
            for (int c = 0; c < 8; c++) {
                float4 w = Wr4[lane*8 + c];
                gl[0] += xl[c]*w.x; gl[1] += xl[c]*w.y;
                gl[2] += xl[c]*w.z; gl[3] += xl[c]*w.w;
            }
        }
        {
            const float4* Wg4 = (const float4*)Wgate;
            #pragma unroll
            for (int g = 0; g < NG; g++) {
                #pragma unroll
                for (int c = 0; c < 8; c++) {
                    float4 w = Wg4[(size_t)g*DIM + lane*8 + c];
                    el[g*4+0] += xl[c]*w.x; el[g*4+1] += xl[c]*w.y;
                    el[g*4+2] += xl[c]*w.z; el[g*4+3] += xl[c]*w.w;
                }
            }
        }

        #pragma unroll
        for (int g = 0; g < NG; g++)
            #pragma unroll
            for (int s = 32; s; s >>= 1) gl[g] += __shfl_xor(gl[g], s);
        #pragma unroll
        for (int e = 0; e < NE; e++)
            #pragma unroll
            for (int s = 32; s; s >>= 1) el[e] += __shfl_xor(el[e], s);

        if (lane != 0) return;

        float gp[NG];
        float mx = -1e30f;
        #pragma unroll
        for (int g = 0; g < NG; g++) { gl[g] += br[g]; mx = fmaxf(mx, gl[g]); }
        float sum = 0.f;
        #pragma unroll
        for (int g = 0; g < NG; g++) { gp[g] = expf(gl[g] - mx); sum += gp[g]; }
        #pragma unroll
        for (int g = 0; g < NG; g++) gp[g] /= sum;

        int i0 = 0;
        #pragma unroll
        for (int g = 1; g < NG; g++) if (gp[g] > gp[i0]) i0 = g;
        int i1 = -1;
        #pragma unroll
        for (int g = 0; g < NG; g++) { if (g == i0) continue; if (i1 < 0 || gp[g] > gp[i1]) i1 = g; }

        bool act1 = (gp[i0] + gp[i1]) <= 0.9f;
        float mp0 = gp[i0], mp1 = act1 ? gp[i1] : 0.f;
        float inv = 1.f / (mp0 + mp1 + 1e-9f);
        float wg[NG] = {0.f,0.f,0.f,0.f};
        wg[i0] = mp0 * inv;
        wg[i1] = mp1 * inv;

        float tw[NE];
        #pragma unroll
        for (int g = 0; g < NG; g++) {
            float ep[EPG];
            float emx = -1e30f;
            #pragma unroll
            for (int j = 0; j < EPG; j++) {
                float v = el[g*4 + j] + bgate[g*4 + j];
                ep[j] = v; emx = fmaxf(emx, v);
            }
            float es = 0.f;
            #pragma unroll
            for (int j = 0; j < EPG; j++) { ep[j] = expf(ep[j] - emx); es += ep[j]; }
            #pragma unroll
            for (int j = 0; j < EPG; j++) ep[j] /= es;

            int j0 = 0;
            #pragma unroll
            for (int j = 1; j < EPG; j++) if (ep[j] > ep[j0]) j0 = j;
            int j1 = -1;
            #pragma unroll
            for (int j = 0; j < EPG; j++) { if (j == j0) continue; if (j1 < 0 || ep[j] > ep[j1]) j1 = j; }

            bool ea1 = (ep[j0] + ep[j1]) <= 0.9f;
            float e0 = ep[j0], e1 = ea1 ? ep[j1] : 0.f;
            float einv = 1.f / (e0 + e1 + 1e-9f);
            float we[EPG] = {0.f,0.f,0.f,0.f};
            we[j0] = e0 * einv;
            we[j1] = e1 * einv;
            #pragma unroll
            for (int j = 0; j < EPG; j++) tw[g*4 + j] = wg[g] * we[j] * 0.5f;   // SCALE = 1/sqrt(4)
        }

        float* twT = (float*)((char*)ws + WS_TW);
        #pragma unroll
        for (int e = 0; e < NE; e++) twT[(size_t)e*N_TOK + t] = tw[e];
        return;
    }

    // ---- W1/W3 convert+transpose: 512 blocks x 4 tiles of 128k x 128n ----
    int bx = bid - 128;
    int j = tid & 31, i0 = tid >> 5;     // j: n-micro (coalesced read), i0: k-micro
    int tg0 = bx * 4;                    // 2048 tiles (2 mats x 16 e x 64)

    const float* src; u16* dst; int k0, n0;
    float4 v0, v1, v2, v3;

    auto setup = [&](int tg) {
        int mat = tg >> 10, e = (tg >> 6) & 15, w = tg & 63;
        const float* s  = mat ? W3 : W1;
        u16* d = (u16*)((char*)ws + (mat ? WS_W3T : WS_W1T));
        k0 = (w & 3) << 7; n0 = (w >> 2) << 7;   // K=512: 4 k-tiles; N=2048: 16 n-tiles
        src = s + (size_t)e*DIM*HID + (size_t)(k0 + 4*i0)*HID + n0 + 4*j;
        dst = d + (size_t)e*HID*DIM;
    };
    auto issue_loads = [&]() {           // 4 x float4, 512B-contiguous segments
        v0 = *(const float4*)(src);
        v1 = *(const float4*)(src + HID);
        v2 = *(const float4*)(src + 2*HID);
        v3 = *(const float4*)(src + 3*HID);
    };

    setup(tg0);
    issue_loads();

    for (int it = 0; it < 4; ++it) {
        u16* dstc = dst; int k0c = k0, n0c = n0;
        u16* Tb = &T[it & 1][0];

        int pc = 4 * (i0 ^ ((j & 15) << 1));
        union { u16 h[4]; uint2 q; } p;
        p.h[0]=f2b(v0.x); p.h[1]=f2b(v1.x); p.h[2]=f2b(v2.x); p.h[3]=f2b(v3.x);
        *(uint2*)(&Tb[(4*j+0)*128 + pc]) = p.q;
        p.h[0]=f2b(v0.y); p.h[1]=f2b(v1.y); p.h[2]=f2b(v2.y); p.h[3]=f2b(v3.y);
        *(uint2*)(&Tb[(4*j+1)*128 + pc]) = p.q;
        p.h[0]=f2b(v0.z); p.h[1]=f2b(v1.z); p.h[2]=f2b(v2.z); p.h[3]=f2b(v3.z);
        *(uint2*)(&Tb[(4*j+2)*128 + pc]) = p.q;
        p.h[0]=f2b(v0.w); p.h[1]=f2b(v1.w); p.h[2]=f2b(v2.w); p.h[3]=f2b(v3.w);
        *(uint2*)(&Tb[(4*j+3)*128 + pc]) = p.q;

        if (it + 1 < 4) { setup(tg0 + it + 1); issue_loads(); }

        asm volatile("s_waitcnt lgkmcnt(0)" ::: "memory");
        __builtin_amdgcn_s_barrier();

        #pragma unroll
        for (int ph = 0; ph < 2; ++ph) {
            int idx = tid + ph*1024;
            int nr = idx >> 4, sg = idx & 15;
            int cp = (2*sg) ^ (((nr >> 2) & 15) << 1);
            *(s16x8*)(dstc + (size_t)(n0c+nr)*DIM + k0c + sg*8) = *(const s16x8*)(&Tb[nr*128 + 4*cp]);
        }
    }
}

// ---- expert lists + scan + slot map: 16 waves, two ballot passes, no atomics ----
__global__ __launch_bounds__(1024) void expert_scan_kernel(void* ws)
{
    int tid = threadIdx.x;
    int e = tid >> 6, lane = tid & 63;
    const float* twT = (const float*)((char*)ws + WS_TW) + (size_t)e*N_TOK;
    int* tok = ws_i32(ws, WS_TOKIDX) + e*MAXT;
    __shared__ int scnt[NE];
    __shared__ int soff[NE+1];

    float v[32];
    #pragma unroll
    for (int r = 0; r < 32; r++) v[r] = twT[r*64 + lane];

    unsigned long long lanemask = (1ull << lane) - 1ull;
    int base = 0;
    #pragma unroll
    for (int r = 0; r < 32; r++) {
        bool a = v[r] > 0.f;
        unsigned long long m = __ballot(a);
        if (a) tok[base + __popcll(m & lanemask)] = r*64 + lane;
        base += __popcll(m);
    }
    if (lane == 0) scnt[e] = base;
    __syncthreads();
    if (tid == 0) {
        int* cnt = ws_i32(ws, WS_CNT);
        int* off = ws_i32(ws, WS_OFF);
        int s = 0;
        for (int i = 0; i < NE; i++) { cnt[i] = scnt[i]; off[i] = s; soff[i] = s; s += scnt[i]; }
        off[NE] = s; soff[NE] = s;
    }
    __syncthreads();

    // pass 2: global slot per (e,t), -1 if inactive
    int* slot_of = ws_i32(ws, WS_SLOT) + e*N_TOK;
    int base2 = soff[e];
    #pragma unroll
    for (int r = 0; r < 32; r++) {
        bool a = v[r] > 0.f;
        unsigned long long m = __ballot(a);
        int pre = __popcll(m & lanemask);
        slot_of[r*64 + lane] = a ? (base2 + pre) : -1;
        base2 += __popcll(m);
    }
}

// ---------------- GEMM1 + W2 transpose (z==NE): hbuf = bf16( silu(X W1) * (X W3) ) ----------------
// K-loop is double-buffered with COUNTED vmcnt across raw s_barrier (T3/T4-min):
// next tile's 10 global_load_lds stay in flight during MFMA; no vmcnt(0) drain.
// LDS: 2 x 40 KB buffers = 80 KB -> 2 blocks/CU.
__global__ __launch_bounds__(256) void gemm1_fast(const float* __restrict__ W2, void* ws)
{
    __shared__ __align__(16) u16 SM[40960];   // 80 KB
    int z = blockIdx.z;
    int tid = threadIdx.x;

    if (z == NE) {
        // ---- W2 [e][2048k][512n] fp32 -> W2T [e][512n][2048k] bf16, 2 tiles of 128x128 ----
        u16* T2 = SM;                              // first 32 KB
        u16* W2T = (u16*)((char*)ws + WS_W2T);
        int slot = blockIdx.x + 16*blockIdx.y;     // [0,512)
        int j = tid & 31, i = tid >> 5;            // j: n-micro, i: k-micro [0,8)
        #pragma unroll 1
        for (int tt = 0; tt < 2; ++tt) {
            int tile = slot + tt*512;              // [0,1024)
            int e = tile >> 6, w = tile & 63;
            int k0 = (w & 15) << 7, n0 = (w >> 4) << 7;   // K=2048: 16 k-tiles; N=512: 4 n-tiles
            const float* s = W2 + (size_t)e*HID*DIM + (size_t)k0*DIM + n0 + 4*j;
            if (tt) __syncthreads();
            #pragma unroll
            for (int c = 0; c < 4; ++c) {
                int kb = 4*i + 32*c;
                const float* base = s + (size_t)kb*DIM;
                float4 v0 = *(const float4*)(base);
                float4 v1 = *(const float4*)(base + DIM);
                float4 v2 = *(const float4*)(base + 2*DIM);
                float4 v3 = *(const float4*)(base + 3*DIM);
                int pc = 4 * ((i + 8*c) ^ ((j & 15) << 1));
                union { u16 h[4]; uint2 q; } p;
                p.h[0]=f2b(v0.x); p.h[1]=f2b(v1.x); p.h[2]=f2b(v2.x); p.h[3]=f2b(v3.x);
                *(uint2*)(&T2[(4*j+0)*128 + pc]) = p.q;
                p.h[0]=f2b(v0.y); p.h[1]=f2b(v1.y); p.h[2]=f2b(v2.y); p.h[3]=f2b(v3.y);
                *(uint2*)(&T2[(4*j+1)*128 + pc]) = p.q;
                p.h[0]=f2b(v0.z); p.h[1]=f2b(v1.z); p.h[2]=f2b(v2.z); p.h[3]=f2b(v3.z);
                *(uint2*)(&T2[(4*j+2)*128 + pc]) = p.q;
                p.h[0]=f2b(v0.w); p.h[1]=f2b(v1.w); p.h[2]=f2b(v2.w); p.h[3]=f2b(v3.w);
                *(uint2*)(&T2[(4*j+3)*128 + pc]) = p.q;
            }
            __syncthreads();
            u16* d = W2T + (size_t)e*DIM*HID;
            #pragma unroll
            for (int ph = 0; ph < 8; ++ph) {
                int idx = tid + ph*256;
                int nr = idx >> 4, sg = idx & 15;
                int cp = (2*sg) ^ (((nr >> 2) & 15) << 1);
                *(s16x8*)(d + (size_t)(n0+nr)*HID + k0 + sg*8) = *(const s16x8*)(&T2[nr*128 + 4*cp]);
            }
        }
        return;
    }

    int e  = z;
    const int* cnt = ws_i32(ws, WS_CNT);
    int ce = cnt[e];
    int m0 = blockIdx.y * BM;
    if (m0 >= ce) return;
    int n0 = blockIdx.x * BN;

    const int* off = ws_i32(ws, WS_OFF);
    const int* tok = ws_i32(ws, WS_TOKIDX) + e*MAXT;
    const u16* xb  = (const u16*)((char*)ws + WS_XB);
    const u16* W1T = (const u16*)((char*)ws + WS_W1T) + (size_t)e*HID*DIM;  // [n][k]
    const u16* W3T = (const u16*)((char*)ws + WS_W3T) + (size_t)e*HID*DIM;
    u16* hbuf = (u16*)((char*)ws + WS_HBUF);
    int obase = off[e] + m0;

    int wave = tid >> 6, lane = tid & 63;
    int quad = lane >> 4, l16 = lane & 15;
    int swz  = l16 & 7;
    int r8 = lane >> 3, sg = lane & 7;
    int swk = ((sg ^ r8) << 3);      // swizzle folded into global k-offset

    // token rows direct from global (L2-hit), clamped to ce-1
    int m_a0 = m0 + wave*16 + r8;     if (m_a0 >= ce) m_a0 = ce - 1;
    int m_a1 = m0 + wave*16 + 8 + r8; if (m_a1 >= ce) m_a1 = ce - 1;
    const u16* arow0 = xb + (size_t)tok[m_a0]*DIM + swk;
    const u16* arow1 = xb + (size_t)tok[m_a1]*DIM + swk;
    const u16* b1row[4]; const u16* b3row[4];
    #pragma unroll
    for (int i = 0; i < 4; i++) {
        size_t nr = (size_t)(n0 + wave*32 + i*8 + r8)*DIM + swk;
        b1row[i] = W1T + nr;
        b3row[i] = W3T + nr;
    }

    f32x4 acc1[4][2], acc3[4][2];
    #pragma unroll
    for (int mt = 0; mt < 4; mt++)
        #pragma unroll
        for (int nt = 0; nt < 2; nt++) {
            acc1[mt][nt] = (f32x4){0.f,0.f,0.f,0.f};
            acc3[mt][nt] = (f32x4){0.f,0.f,0.f,0.f};
        }

    // buffer layout (u16 units): buf b at SM + b*20480: As 4096 | Bs0 8192 | Bs1 8192
    auto stage = [&](int b, int k0) {
        u16* As_  = SM + b*20480;
        u16* Bs0_ = As_ + 4096;
        u16* Bs1_ = As_ + 12288;
        gl_lds16(arow0 + k0, &As_[(wave*16)*BK]);
        gl_lds16(arow1 + k0, &As_[(wave*16 + 8)*BK]);
        #pragma unroll
        for (int i = 0; i < 4; i++) {
            gl_lds16(b1row[i] + k0, &Bs0_[(wave*32 + i*8)*BK]);
            gl_lds16(b3row[i] + k0, &Bs1_[(wave*32 + i*8)*BK]);
        }
    };
    auto compute = [&](int b) {
        u16* As_  = SM + b*20480;
        u16* Bs0_ = As_ + 4096;
        u16* Bs1_ = As_ + 12288;
        #pragma unroll
        for (int kk = 0; kk < BK; kk += 32) {
            int jj = (kk >> 3) + quad;
            int so = ((jj ^ swz) << 3);
            s16x8 af[4];
            #pragma unroll
            for (int mt = 0; mt < 4; mt++)
                af[mt] = *(const s16x8*)(&As_[(mt*16 + l16)*BK + so]);
            #pragma unroll
            for (int nt = 0; nt < 2; nt++) {
                int n = wave*32 + nt*16 + l16;
                s16x8 b1 = *(const s16x8*)(&Bs0_[n*BK + so]);
                s16x8 b3 = *(const s16x8*)(&Bs1_[n*BK + so]);
                #pragma unroll
                for (int mt = 0; mt < 4; mt++) {
                    acc1[mt][nt] = __builtin_amdgcn_mfma_f32_16x16x32_bf16(af[mt], b1, acc1[mt][nt], 0, 0, 0);
                    acc3[mt][nt] = __builtin_amdgcn_mfma_f32_16x16x32_bf16(af[mt], b3, acc3[mt][nt], 0, 0, 0);
                }
            }
        }
    };

    stage(0, 0);
    #pragma unroll 1
    for (int kt = 0; kt < 7; ++kt) {
        int cur = kt & 1;
        stage(cur ^ 1, (kt + 1)*BK);                 // 10 loads -> in flight over compute
        asm volatile("s_waitcnt vmcnt(10)" ::: "memory");  // cur's loads landed
        __builtin_amdgcn_s_barrier();
        asm volatile("" ::: "memory");
        compute(cur);
        __builtin_amdgcn_s_barrier();                // cur reads done -> overwrite ok next iter
        asm volatile("" ::: "memory");
    }
    asm volatile("s_waitcnt vmcnt(0)" ::: "memory");
    __builtin_amdgcn_s_barrier();
    asm volatile("" ::: "memory");
    compute(1);                                      // kt = 7

    #pragma unroll
    for (int mt = 0; mt < 4; mt++) {
        #pragma unroll
        for (int r = 0; r < 4; r++) {
            int row = mt*16 + quad*4 + r;
            if (m0 + row < ce) {
                #pragma unroll
                for (int nt = 0; nt < 2; nt++) {
                    float a = acc1[mt][nt][r];
                    float b = acc3[mt][nt][r];
                    float h = (a / (1.f + expf(-a))) * b;
                    int col = wave*32 + nt*16 + l16;
                    hbuf[(size_t)(obase + row)*HID + n0 + col] = f2b(h);
                }
            }
        }
    }
}

// ---------------- GEMM2: buf2 = tw * (h W2), double-buffered counted-vmcnt K-loop ----------------
__global__ __launch_bounds__(256) void gemm2_fast(void* ws)
{
    __shared__ __align__(16) u16 SM[24576];   // 48 KB: 2 x (As 8KB | Bs 16KB)
    int e  = blockIdx.z;
    const int* cnt = ws_i32(ws, WS_CNT);
    int ce = cnt[e];
    int m0 = blockIdx.y * BM;
    if (m0 >= ce) return;
    int n0 = blockIdx.x * BN;

    const int* off = ws_i32(ws, WS_OFF);
    const int* tok = ws_i32(ws, WS_TOKIDX) + e*MAXT;
    const float* twT = (const float*)((char*)ws + WS_TW);
    const u16* hbuf = (const u16*)((char*)ws + WS_HBUF);
    const u16* W2T = (const u16*)((char*)ws + WS_W2T) + (size_t)e*DIM*HID;  // [n=512][k=2048]
    float* buf2 = (float*)((char*)ws + WS_BUF2);
    int abase = off[e] + m0;
    int total = off[NE];

    int tid = threadIdx.x;
    int wave = tid >> 6, lane = tid & 63;
    int quad = lane >> 4, l16 = lane & 15;
    int swz  = l16 & 7;
    int r8 = lane >> 3, sg = lane & 7;
    int swk = ((sg ^ r8) << 3);

    int ar0 = abase + wave*16 + r8;      if (ar0 > total - 1) ar0 = total - 1;
    int ar1 = abase + wave*16 + 8 + r8;  if (ar1 > total - 1) ar1 = total - 1;
    const u16* arow0 = hbuf + (size_t)ar0*HID + swk;
    const u16* arow1 = hbuf + (size_t)ar1*HID + swk;
    const u16* brow[4];
    #pragma unroll
    for (int i = 0; i < 4; i++)
        brow[i] = W2T + (size_t)(n0 + wave*32 + i*8 + r8)*HID + swk;

    f32x4 acc[4][2];
    #pragma unroll
    for (int mt = 0; mt < 4; mt++)
        #pragma unroll
        for (int nt = 0; nt < 2; nt++) acc[mt][nt] = (f32x4){0.f,0.f,0.f,0.f};

    auto stage = [&](int b, int k0) {
        u16* As_ = SM + b*12288;
        u16* Bs_ = As_ + 4096;
        gl_lds16(arow0 + k0, &As_[(wave*16)*BK]);
        gl_lds16(arow1 + k0, &As_[(wave*16 + 8)*BK]);
        #pragma unroll
        for (int i = 0; i < 4; i++)
            gl_lds16(brow[i] + k0, &Bs_[(wave*32 + i*8)*BK]);
    };
    auto compute = [&](int b) {
        u16* As_ = SM + b*12288;
        u16* Bs_ = As_ + 4096;
        #pragma unroll
        for (int kk = 0; kk < BK; kk += 32) {
            int jj = (kk >> 3) + quad;
            int so = ((jj ^ swz) << 3);
            s16x8 af[4];
            #pragma unroll
            for (int mt = 0; mt < 4; mt++)
                af[mt] = *(const s16x8*)(&As_[(mt*16 + l16)*BK + so]);
            #pragma unroll
            for (int nt = 0; nt < 2; nt++) {
                int n = wave*32 + nt*16 + l16;
                s16x8 bfr = *(const s16x8*)(&Bs_[n*BK + so]);
                #pragma unroll
                for (int mt = 0; mt < 4; mt++)
                    acc[mt][nt] = __builtin_amdgcn_mfma_f32_16x16x32_bf16(af[mt], bfr, acc[mt][nt], 0, 0, 0);
            }
        }
    };

    stage(0, 0);
    #pragma unroll 1
    for (int kt = 0; kt < 31; ++kt) {
        int cur = kt & 1;
        stage(cur ^ 1, (kt + 1)*BK);                 // 6 loads in flight over compute
        asm volatile("s_waitcnt vmcnt(6)" ::: "memory");
        __builtin_amdgcn_s_barrier();
        asm volatile("" ::: "memory");
        compute(cur);
        __builtin_amdgcn_s_barrier();
        asm volatile("" ::: "memory");
    }
    asm volatile("s_waitcnt vmcnt(0)" ::: "memory");
    __builtin_amdgcn_s_barrier();
    asm volatile("" ::: "memory");
    compute(1);                                      // kt = 31

    #pragma unroll
    for (int mt = 0; mt < 4; mt++) {
        #pragma unroll
        for (int r = 0; r < 4; r++) {
            int row = mt*16 + quad*4 + r;
            if (m0 + row < ce) {
                int t = tok[m0 + row];
                float s = twT[(size_t)e*N_TOK + t];
                #pragma unroll
                for (int nt = 0; nt < 2; nt++) {
                    int col = wave*32 + nt*16 + l16;
                    buf2[(size_t)(abase + row)*DIM + n0 + col] = acc[mt][nt][r] * s;
                }
            }
        }
    }
}

// ---------------- gather: out[t] = sum of buf2 rows for t's active experts ----------------
__global__ __launch_bounds__(128) void gather_kernel(void* ws, float* __restrict__ out)
{
    int t = blockIdx.x;
    int tid = threadIdx.x;
    const int* slot_of = ws_i32(ws, WS_SLOT);
    const float* buf2 = (const float*)((char*)ws + WS_BUF2);

    int d = tid * 4;
    float4 acc = {0.f, 0.f, 0.f, 0.f};
    #pragma unroll
    for (int e = 0; e < NE; e++) {
        int s = slot_of[e*N_TOK + t];      // wave-uniform per block
        if (s >= 0) {
            float4 v = *(const float4*)(buf2 + (size_t)s*DIM + d);
            acc.x += v.x; acc.y += v.y; acc.z += v.z; acc.w += v.w;
        }
    }
    *(float4*)(out + (size_t)t*DIM + d) = acc;
}

extern "C" void kernel_launch(void* const* d_in, const int* in_sizes, int n_in,
                              void* d_out, int out_size, void* d_ws, size_t ws_size,
                              hipStream_t stream)
{
    const float* x     = (const float*)d_in[0];
    const float* Wr    = (const float*)d_in[1];
    const float* br    = (const float*)d_in[2];
    const float* Wgate = (const float*)d_in[3];
    const float* bgate = (const float*)d_in[4];
    const float* W1    = (const float*)d_in[5];
    const float* W3    = (const float*)d_in[6];
    const float* W2    = (const float*)d_in[7];
    float* out = (float*)d_out;

    prep_kernel<<<640, 1024, 0, stream>>>(x, Wr, br, Wgate, bgate, W1, W3, d_ws);
    expert_scan_kernel<<<1, 1024, 0, stream>>>(d_ws);
    gemm1_fast<<<dim3(HID/BN, N_TOK/BM, NE + 1), 256, 0, stream>>>(W2, d_ws);
    gemm2_fast<<<dim3(DIM/BN, N_TOK/BM, NE), 256, 0, stream>>>(d_ws);
    gather_kernel<<<N_TOK, 128, 0, stream>>>(d_ws, out);
}

// Round 6
// 323.292 us; speedup vs baseline: 1.1087x; 1.0090x over previous
//
#include <hip/hip_runtime.h>
#include <math.h>

typedef unsigned short u16;
typedef unsigned int   u32;
typedef short s16x8 __attribute__((ext_vector_type(8)));
typedef float f32x4 __attribute__((ext_vector_type(4)));

#define N_TOK 2048
#define DIM   512
#define HID   2048
#define NE    16
#define NG    4
#define EPG   4
#define MAXT  2048

#define BM 64
#define BN 128
#define BK 64

// ---- workspace layout (bytes) ----
#define WS_CNT    0                              // 16 ints
#define WS_OFF    128                            // 17 ints
#define WS_TOKIDX 256                            // 16*2048 ints
#define WS_TW     (WS_TOKIDX + NE*MAXT*4)        // twT[e][t]: 16*2048 f32
#define WS_XB     (WS_TW + N_TOK*NE*4)           // 2048*512 u16 (bf16 x)
#define WS_HBUF   (WS_XB + (size_t)N_TOK*DIM*2)  // 8192*2048 u16
#define WS_W1T    (WS_HBUF + (size_t)8192*HID*2) // 16*2048*512 u16 (bf16 W1^T [e][n][k])
#define WS_W3T    (WS_W1T + (size_t)NE*HID*DIM*2)
#define WS_W2T    (WS_W3T + (size_t)NE*HID*DIM*2) // 16*512*2048 u16 (bf16 W2^T [e][n][k])
#define WS_SLOT   (WS_W2T + (size_t)NE*DIM*HID*2) // slot_of[e][t]: 16*2048 ints
// buf2 (8192*512 f32 = 16.8 MB) aliases W1T: W1T is dead once gemm1 completes,
// buf2 is written by gemm2 (after gemm1) and read by gather. Safe within one call
// and across graph replays (prep rewrites W1T first each call).
#define WS_BUF2   WS_W1T

__device__ __forceinline__ int* ws_i32(void* ws, size_t off) { return (int*)((char*)ws + off); }

__device__ __forceinline__ u16 f2b(float f) {   // fp32 -> bf16 RNE
    union { float f; u32 i; } v; v.f = f;
    u32 b = v.i;
    u32 r = b + 0x7FFFu + ((b >> 16) & 1u);
    return (u16)(r >> 16);
}

// async global->LDS, 16B/lane; LDS side is wave-uniform base + lane*16
__device__ __forceinline__ void gl_lds16(const u16* g, u16* l) {
    __builtin_amdgcn_global_load_lds((const __attribute__((address_space(1))) void*)g,
                                     (__attribute__((address_space(3))) void*)l, 16, 0, 0);
}

// ---------------- prep: routing (128 blocks) + W1/W3 convert-transpose (512 blocks) ----------------
__global__ __launch_bounds__(1024) void prep_kernel(
    const float* __restrict__ x, const float* __restrict__ Wr, const float* __restrict__ br,
    const float* __restrict__ Wgate, const float* __restrict__ bgate,
    const float* __restrict__ W1, const float* __restrict__ W3, void* ws)
{
    __shared__ u16 T[2][128*128];   // 2 x 32 KB (transpose path only)
    int tid = threadIdx.x;
    int bid = blockIdx.x;

    if (bid < 128) {
        // ---- routing: 16 waves, one token per wave ----
        int t = bid * 16 + (tid >> 6);
        int lane = tid & 63;

        float xl[8];
        {
            const float4* xr = (const float4*)(x + (size_t)t*DIM + lane*8);
            float4 a = xr[0], b = xr[1];
            xl[0]=a.x; xl[1]=a.y; xl[2]=a.z; xl[3]=a.w;
            xl[4]=b.x; xl[5]=b.y; xl[6]=b.z; xl[7]=b.w;
        }
        {
            union { u16 h[8]; uint4 q; } pk;
            #pragma unroll
            for (int i = 0; i < 8; i++) pk.h[i] = f2b(xl[i]);
            u16* xb = (u16*)((char*)ws + WS_XB);
            *(uint4*)(xb + (size_t)t*DIM + lane*8) = pk.q;
        }

        float gl[NG] = {0.f,0.f,0.f,0.f};
        float el[NE];
        #pragma unroll
        for (int e = 0; e < NE; e++) el[e] = 0.f;

        {
            const float4* Wr4 = (const float4*)Wr;
            #pragma unroll
            for (int c = 0; c < 8; c++) {
                float4 w = Wr4[lane*8 + c];
                gl[0] += xl[c]*w.x; gl[1] += xl[c]*w.y;
                gl[2] += xl[c]*w.z; gl[3] += xl[c]*w.w;
            }
        }
        {
            const float4* Wg4 = (const float4*)Wgate;
            #pragma unroll
            for (int g = 0; g < NG; g++) {
                #pragma unroll
                for (int c = 0; c < 8; c++) {
                    float4 w = Wg4[(size_t)g*DIM + lane*8 + c];
                    el[g*4+0] += xl[c]*w.x; el[g*4+1] += xl[c]*w.y;
                    el[g*4+2] += xl[c]*w.z; el[g*4+3] += xl[c]*w.w;
                }
            }
        }

        #pragma unroll
        for (int g = 0; g < NG; g++)
            #pragma unroll
            for (int s = 32; s; s >>= 1) gl[g] += __shfl_xor(gl[g], s);
        #pragma unroll
        for (int e = 0; e < NE; e++)
            #pragma unroll
            for (int s = 32; s; s >>= 1) el[e] += __shfl_xor(el[e], s);

        if (lane != 0) return;

        float gp[NG];
        float mx = -1e30f;
        #pragma unroll
        for (int g = 0; g < NG; g++) { gl[g] += br[g]; mx = fmaxf(mx, gl[g]); }
        float sum = 0.f;
        #pragma unroll
        for (int g = 0; g < NG; g++) { gp[g] = expf(gl[g] - mx); sum += gp[g]; }
        #pragma unroll
        for (int g = 0; g < NG; g++) gp[g] /= sum;

        int i0 = 0;
        #pragma unroll
        for (int g = 1; g < NG; g++) if (gp[g] > gp[i0]) i0 = g;
        int i1 = -1;
        #pragma unroll
        for (int g = 0; g < NG; g++) { if (g == i0) continue; if (i1 < 0 || gp[g] > gp[i1]) i1 = g; }

        bool act1 = (gp[i0] + gp[i1]) <= 0.9f;
        float mp0 = gp[i0], mp1 = act1 ? gp[i1] : 0.f;
        float inv = 1.f / (mp0 + mp1 + 1e-9f);
        float wg[NG] = {0.f,0.f,0.f,0.f};
        wg[i0] = mp0 * inv;
        wg[i1] = mp1 * inv;

        float tw[NE];
        #pragma unroll
        for (int g = 0; g < NG; g++) {
            float ep[EPG];
            float emx = -1e30f;
            #pragma unroll
            for (int j = 0; j < EPG; j++) {
                float v = el[g*4 + j] + bgate[g*4 + j];
                ep[j] = v; emx = fmaxf(emx, v);
            }
            float es = 0.f;
            #pragma unroll
            for (int j = 0; j < EPG; j++) { ep[j] = expf(ep[j] - emx); es += ep[j]; }
            #pragma unroll
            for (int j = 0; j < EPG; j++) ep[j] /= es;

            int j0 = 0;
            #pragma unroll
            for (int j = 1; j < EPG; j++) if (ep[j] > ep[j0]) j0 = j;
            int j1 = -1;
            #pragma unroll
            for (int j = 0; j < EPG; j++) { if (j == j0) continue; if (j1 < 0 || ep[j] > ep[j1]) j1 = j; }

            bool ea1 = (ep[j0] + ep[j1]) <= 0.9f;
            float e0 = ep[j0], e1 = ea1 ? ep[j1] : 0.f;
            float einv = 1.f / (e0 + e1 + 1e-9f);
            float we[EPG] = {0.f,0.f,0.f,0.f};
            we[j0] = e0 * einv;
            we[j1] = e1 * einv;
            #pragma unroll
            for (int j = 0; j < EPG; j++) tw[g*4 + j] = wg[g] * we[j] * 0.5f;   // SCALE = 1/sqrt(4)
        }

        float* twT = (float*)((char*)ws + WS_TW);
        #pragma unroll
        for (int e = 0; e < NE; e++) twT[(size_t)e*N_TOK + t] = tw[e];
        return;
    }

    // ---- W1/W3 convert+transpose: 512 blocks x 4 tiles of 128k x 128n ----
    int bx = bid - 128;
    int j = tid & 31, i0 = tid >> 5;     // j: n-micro (coalesced read), i0: k-micro
    int tg0 = bx * 4;                    // 2048 tiles (2 mats x 16 e x 64)

    const float* src; u16* dst; int k0, n0;
    float4 v0, v1, v2, v3;

    auto setup = [&](int tg) {
        int mat = tg >> 10, e = (tg >> 6) & 15, w = tg & 63;
        const float* s  = mat ? W3 : W1;
        u16* d = (u16*)((char*)ws + (mat ? WS_W3T : WS_W1T));
        k0 = (w & 3) << 7; n0 = (w >> 2) << 7;   // K=512: 4 k-tiles; N=2048: 16 n-tiles
        src = s + (size_t)e*DIM*HID + (size_t)(k0 + 4*i0)*HID + n0 + 4*j;
        dst = d + (size_t)e*HID*DIM;
    };
    auto issue_loads = [&]() {           // 4 x float4, 512B-contiguous segments
        v0 = *(const float4*)(src);
        v1 = *(const float4*)(src + HID);
        v2 = *(const float4*)(src + 2*HID);
        v3 = *(const float4*)(src + 3*HID);
    };

    setup(tg0);
    issue_loads();

    for (int it = 0; it < 4; ++it) {
        u16* dstc = dst; int k0c = k0, n0c = n0;
        u16* Tb = &T[it & 1][0];

        int pc = 4 * (i0 ^ ((j & 15) << 1));
        union { u16 h[4]; uint2 q; } p;
        p.h[0]=f2b(v0.x); p.h[1]=f2b(v1.x); p.h[2]=f2b(v2.x); p.h[3]=f2b(v3.x);
        *(uint2*)(&Tb[(4*j+0)*128 + pc]) = p.q;
        p.h[0]=f2b(v0.y); p.h[1]=f2b(v1.y); p.h[2]=f2b(v2.y); p.h[3]=f2b(v3.y);
        *(uint2*)(&Tb[(4*j+1)*128 + pc]) = p.q;
        p.h[0]=f2b(v0.z); p.h[1]=f2b(v1.z); p.h[2]=f2b(v2.z); p.h[3]=f2b(v3.z);
        *(uint2*)(&Tb[(4*j+2)*128 + pc]) = p.q;
        p.h[0]=f2b(v0.w); p.h[1]=f2b(v1.w); p.h[2]=f2b(v2.w); p.h[3]=f2b(v3.w);
        *(uint2*)(&Tb[(4*j+3)*128 + pc]) = p.q;

        if (it + 1 < 4) { setup(tg0 + it + 1); issue_loads(); }

        asm volatile("s_waitcnt lgkmcnt(0)" ::: "memory");
        __builtin_amdgcn_s_barrier();

        #pragma unroll
        for (int ph = 0; ph < 2; ++ph) {
            int idx = tid + ph*1024;
            int nr = idx >> 4, sg = idx & 15;
            int cp = (2*sg) ^ (((nr >> 2) & 15) << 1);
            *(s16x8*)(dstc + (size_t)(n0c+nr)*DIM + k0c + sg*8) = *(const s16x8*)(&Tb[nr*128 + 4*cp]);
        }
    }
}

// ---- expert lists + scan + slot map: 16 waves, two ballot passes, no atomics ----
__global__ __launch_bounds__(1024) void expert_scan_kernel(void* ws)
{
    int tid = threadIdx.x;
    int e = tid >> 6, lane = tid & 63;
    const float* twT = (const float*)((char*)ws + WS_TW) + (size_t)e*N_TOK;
    int* tok = ws_i32(ws, WS_TOKIDX) + e*MAXT;
    __shared__ int scnt[NE];
    __shared__ int soff[NE+1];

    float v[32];
    #pragma unroll
    for (int r = 0; r < 32; r++) v[r] = twT[r*64 + lane];

    unsigned long long lanemask = (1ull << lane) - 1ull;
    int base = 0;
    #pragma unroll
    for (int r = 0; r < 32; r++) {
        bool a = v[r] > 0.f;
        unsigned long long m = __ballot(a);
        if (a) tok[base + __popcll(m & lanemask)] = r*64 + lane;
        base += __popcll(m);
    }
    if (lane == 0) scnt[e] = base;
    __syncthreads();
    if (tid == 0) {
        int* cnt = ws_i32(ws, WS_CNT);
        int* off = ws_i32(ws, WS_OFF);
        int s = 0;
        for (int i = 0; i < NE; i++) { cnt[i] = scnt[i]; off[i] = s; soff[i] = s; s += scnt[i]; }
        off[NE] = s; soff[NE] = s;
    }
    __syncthreads();

    // pass 2: global slot per (e,t), -1 if inactive
    int* slot_of = ws_i32(ws, WS_SLOT) + e*N_TOK;
    int base2 = soff[e];
    #pragma unroll
    for (int r = 0; r < 32; r++) {
        bool a = v[r] > 0.f;
        unsigned long long m = __ballot(a);
        int pre = __popcll(m & lanemask);
        slot_of[r*64 + lane] = a ? (base2 + pre) : -1;
        base2 += __popcll(m);
    }
}

// ---------------- GEMM1 + W2 transpose (z==NE): hbuf = bf16( silu(X W1) * (X W3) ) ----------------
// Double-buffered K-loop, STATICALLY unrolled ping-pong (round-6 fix): every stage/
// compute gets a literal LDS base so all addresses fold to static offsets (round-5's
// runtime `b*20480` indexing cost +16% VALUBusy). Counted vmcnt(10) across raw
// s_barrier keeps next tile's loads in flight over MFMA.
__global__ __launch_bounds__(256) void gemm1_fast(const float* __restrict__ W2, void* ws)
{
    __shared__ __align__(16) u16 SM[40960];   // 80 KB: 2 x (As 8KB | Bs0 16KB | Bs1 16KB)
    int z = blockIdx.z;
    int tid = threadIdx.x;

    if (z == NE) {
        // ---- W2 [e][2048k][512n] fp32 -> W2T [e][512n][2048k] bf16, 2 tiles of 128x128 ----
        u16* T2 = SM;                              // first 32 KB
        u16* W2T = (u16*)((char*)ws + WS_W2T);
        int slot = blockIdx.x + 16*blockIdx.y;     // [0,512)
        int j = tid & 31, i = tid >> 5;            // j: n-micro, i: k-micro [0,8)
        #pragma unroll 1
        for (int tt = 0; tt < 2; ++tt) {
            int tile = slot + tt*512;              // [0,1024)
            int e = tile >> 6, w = tile & 63;
            int k0 = (w & 15) << 7, n0 = (w >> 4) << 7;   // K=2048: 16 k-tiles; N=512: 4 n-tiles
            const float* s = W2 + (size_t)e*HID*DIM + (size_t)k0*DIM + n0 + 4*j;
            if (tt) __syncthreads();
            #pragma unroll
            for (int c = 0; c < 4; ++c) {
                int kb = 4*i + 32*c;
                const float* base = s + (size_t)kb*DIM;
                float4 v0 = *(const float4*)(base);
                float4 v1 = *(const float4*)(base + DIM);
                float4 v2 = *(const float4*)(base + 2*DIM);
                float4 v3 = *(const float4*)(base + 3*DIM);
                int pc = 4 * ((i + 8*c) ^ ((j & 15) << 1));
                union { u16 h[4]; uint2 q; } p;
                p.h[0]=f2b(v0.x); p.h[1]=f2b(v1.x); p.h[2]=f2b(v2.x); p.h[3]=f2b(v3.x);
                *(uint2*)(&T2[(4*j+0)*128 + pc]) = p.q;
                p.h[0]=f2b(v0.y); p.h[1]=f2b(v1.y); p.h[2]=f2b(v2.y); p.h[3]=f2b(v3.y);
                *(uint2*)(&T2[(4*j+1)*128 + pc]) = p.q;
                p.h[0]=f2b(v0.z); p.h[1]=f2b(v1.z); p.h[2]=f2b(v2.z); p.h[3]=f2b(v3.z);
                *(uint2*)(&T2[(4*j+2)*128 + pc]) = p.q;
                p.h[0]=f2b(v0.w); p.h[1]=f2b(v1.w); p.h[2]=f2b(v2.w); p.h[3]=f2b(v3.w);
                *(uint2*)(&T2[(4*j+3)*128 + pc]) = p.q;
            }
            __syncthreads();
            u16* d = W2T + (size_t)e*DIM*HID;
            #pragma unroll
            for (int ph = 0; ph < 8; ++ph) {
                int idx = tid + ph*256;
                int nr = idx >> 4, sg = idx & 15;
                int cp = (2*sg) ^ (((nr >> 2) & 15) << 1);
                *(s16x8*)(d + (size_t)(n0+nr)*HID + k0 + sg*8) = *(const s16x8*)(&T2[nr*128 + 4*cp]);
            }
        }
        return;
    }

    int e  = z;
    const int* cnt = ws_i32(ws, WS_CNT);
    int ce = cnt[e];
    int m0 = blockIdx.y * BM;
    if (m0 >= ce) return;
    int n0 = blockIdx.x * BN;

    const int* off = ws_i32(ws, WS_OFF);
    const int* tok = ws_i32(ws, WS_TOKIDX) + e*MAXT;
    const u16* xb  = (const u16*)((char*)ws + WS_XB);
    const u16* W1T = (const u16*)((char*)ws + WS_W1T) + (size_t)e*HID*DIM;  // [n][k]
    const u16* W3T = (const u16*)((char*)ws + WS_W3T) + (size_t)e*HID*DIM;
    u16* hbuf = (u16*)((char*)ws + WS_HBUF);
    int obase = off[e] + m0;

    int wave = tid >> 6, lane = tid & 63;
    int quad = lane >> 4, l16 = lane & 15;
    int swz  = l16 & 7;
    int r8 = lane >> 3, sg = lane & 7;
    int swk = ((sg ^ r8) << 3);      // swizzle folded into global k-offset

    // token rows direct from global (L2-hit), clamped to ce-1
    int m_a0 = m0 + wave*16 + r8;     if (m_a0 >= ce) m_a0 = ce - 1;
    int m_a1 = m0 + wave*16 + 8 + r8; if (m_a1 >= ce) m_a1 = ce - 1;
    const u16* arow0 = xb + (size_t)tok[m_a0]*DIM + swk;
    const u16* arow1 = xb + (size_t)tok[m_a1]*DIM + swk;
    const u16* b1row[4]; const u16* b3row[4];
    #pragma unroll
    for (int i = 0; i < 4; i++) {
        size_t nr = (size_t)(n0 + wave*32 + i*8 + r8)*DIM + swk;
        b1row[i] = W1T + nr;
        b3row[i] = W3T + nr;
    }

    f32x4 acc1[4][2], acc3[4][2];
    #pragma unroll
    for (int mt = 0; mt < 4; mt++)
        #pragma unroll
        for (int nt = 0; nt < 2; nt++) {
            acc1[mt][nt] = (f32x4){0.f,0.f,0.f,0.f};
            acc3[mt][nt] = (f32x4){0.f,0.f,0.f,0.f};
        }

    // buffer layout (u16 units): As 4096 | Bs0 8192 | Bs1 8192 ; buf1 at +20480
    auto stage = [&](u16* B, int k0) {
        gl_lds16(arow0 + k0, B + (wave*16)*BK);
        gl_lds16(arow1 + k0, B + (wave*16 + 8)*BK);
        #pragma unroll
        for (int i = 0; i < 4; i++) {
            gl_lds16(b1row[i] + k0, B + 4096 + (wave*32 + i*8)*BK);
            gl_lds16(b3row[i] + k0, B + 12288 + (wave*32 + i*8)*BK);
        }
    };
    auto compute = [&](const u16* B) {
        #pragma unroll
        for (int kk = 0; kk < BK; kk += 32) {
            int jj = (kk >> 3) + quad;
            int so = ((jj ^ swz) << 3);
            s16x8 af[4];
            #pragma unroll
            for (int mt = 0; mt < 4; mt++)
                af[mt] = *(const s16x8*)(B + (mt*16 + l16)*BK + so);
            #pragma unroll
            for (int nt = 0; nt < 2; nt++) {
                int n = wave*32 + nt*16 + l16;
                s16x8 b1 = *(const s16x8*)(B + 4096 + n*BK + so);
                s16x8 b3 = *(const s16x8*)(B + 12288 + n*BK + so);
                #pragma unroll
                for (int mt = 0; mt < 4; mt++) {
                    acc1[mt][nt] = __builtin_amdgcn_mfma_f32_16x16x32_bf16(af[mt], b1, acc1[mt][nt], 0, 0, 0);
                    acc3[mt][nt] = __builtin_amdgcn_mfma_f32_16x16x32_bf16(af[mt], b3, acc3[mt][nt], 0, 0, 0);
                }
            }
        }
    };

    u16* SM0 = SM;
    u16* SM1 = SM + 20480;

    stage(SM0, 0);
    #pragma unroll 1
    for (int kt2 = 0; kt2 < 3; ++kt2) {             // 2 K-steps per iter: k=2*kt2, 2*kt2+1
        int kb = kt2*2*BK;
        stage(SM1, kb + BK);
        asm volatile("s_waitcnt vmcnt(10)" ::: "memory");
        __builtin_amdgcn_s_barrier();
        compute(SM0);
        __builtin_amdgcn_s_barrier();
        stage(SM0, kb + 2*BK);
        asm volatile("s_waitcnt vmcnt(10)" ::: "memory");
        __builtin_amdgcn_s_barrier();
        compute(SM1);
        __builtin_amdgcn_s_barrier();
    }
    // tail: SM0 holds k=6 (in flight), k=7 still to stage
    stage(SM1, 7*BK);
    asm volatile("s_waitcnt vmcnt(10)" ::: "memory");
    __builtin_amdgcn_s_barrier();
    compute(SM0);                                   // k=6
    __builtin_amdgcn_s_barrier();
    asm volatile("s_waitcnt vmcnt(0)" ::: "memory");
    __builtin_amdgcn_s_barrier();
    compute(SM1);                                   // k=7

    #pragma unroll
    for (int mt = 0; mt < 4; mt++) {
        #pragma unroll
        for (int r = 0; r < 4; r++) {
            int row = mt*16 + quad*4 + r;
            if (m0 + row < ce) {
                #pragma unroll
                for (int nt = 0; nt < 2; nt++) {
                    float a = acc1[mt][nt][r];
                    float b = acc3[mt][nt][r];
                    float h = (a / (1.f + expf(-a))) * b;
                    int col = wave*32 + nt*16 + l16;
                    hbuf[(size_t)(obase + row)*HID + n0 + col] = f2b(h);
                }
            }
        }
    }
}

// ---------------- GEMM2: buf2 = tw * (h W2), static ping-pong double-buffer ----------------
__global__ __launch_bounds__(256) void gemm2_fast(void* ws)
{
    __shared__ __align__(16) u16 SM[24576];   // 48 KB: 2 x (As 8KB | Bs 16KB)
    int e  = blockIdx.z;
    const int* cnt = ws_i32(ws, WS_CNT);
    int ce = cnt[e];
    int m0 = blockIdx.y * BM;
    if (m0 >= ce) return;
    int n0 = blockIdx.x * BN;

    const int* off = ws_i32(ws, WS_OFF);
    const int* tok = ws_i32(ws, WS_TOKIDX) + e*MAXT;
    const float* twT = (const float*)((char*)ws + WS_TW);
    const u16* hbuf = (const u16*)((char*)ws + WS_HBUF);
    const u16* W2T = (const u16*)((char*)ws + WS_W2T) + (size_t)e*DIM*HID;  // [n=512][k=2048]
    float* buf2 = (float*)((char*)ws + WS_BUF2);
    int abase = off[e] + m0;
    int total = off[NE];

    int tid = threadIdx.x;
    int wave = tid >> 6, lane = tid & 63;
    int quad = lane >> 4, l16 = lane & 15;
    int swz  = l16 & 7;
    int r8 = lane >> 3, sg = lane & 7;
    int swk = ((sg ^ r8) << 3);

    int ar0 = abase + wave*16 + r8;      if (ar0 > total - 1) ar0 = total - 1;
    int ar1 = abase + wave*16 + 8 + r8;  if (ar1 > total - 1) ar1 = total - 1;
    const u16* arow0 = hbuf + (size_t)ar0*HID + swk;
    const u16* arow1 = hbuf + (size_t)ar1*HID + swk;
    const u16* brow[4];
    #pragma unroll
    for (int i = 0; i < 4; i++)
        brow[i] = W2T + (size_t)(n0 + wave*32 + i*8 + r8)*HID + swk;

    f32x4 acc[4][2];
    #pragma unroll
    for (int mt = 0; mt < 4; mt++)
        #pragma unroll
        for (int nt = 0; nt < 2; nt++) acc[mt][nt] = (f32x4){0.f,0.f,0.f,0.f};

    auto stage = [&](u16* B, int k0) {
        gl_lds16(arow0 + k0, B + (wave*16)*BK);
        gl_lds16(arow1 + k0, B + (wave*16 + 8)*BK);
        #pragma unroll
        for (int i = 0; i < 4; i++)
            gl_lds16(brow[i] + k0, B + 4096 + (wave*32 + i*8)*BK);
    };
    auto compute = [&](const u16* B) {
        #pragma unroll
        for (int kk = 0; kk < BK; kk += 32) {
            int jj = (kk >> 3) + quad;
            int so = ((jj ^ swz) << 3);
            s16x8 af[4];
            #pragma unroll
            for (int mt = 0; mt < 4; mt++)
                af[mt] = *(const s16x8*)(B + (mt*16 + l16)*BK + so);
            #pragma unroll
            for (int nt = 0; nt < 2; nt++) {
                int n = wave*32 + nt*16 + l16;
                s16x8 bfr = *(const s16x8*)(B + 4096 + n*BK + so);
                #pragma unroll
                for (int mt = 0; mt < 4; mt++)
                    acc[mt][nt] = __builtin_amdgcn_mfma_f32_16x16x32_bf16(af[mt], bfr, acc[mt][nt], 0, 0, 0);
            }
        }
    };

    u16* SM0 = SM;
    u16* SM1 = SM + 12288;

    stage(SM0, 0);
    #pragma unroll 1
    for (int kt2 = 0; kt2 < 15; ++kt2) {            // 2 K-steps per iter: 30 of 32
        int kb = kt2*2*BK;
        stage(SM1, kb + BK);
        asm volatile("s_waitcnt vmcnt(6)" ::: "memory");
        __builtin_amdgcn_s_barrier();
        compute(SM0);
        __builtin_amdgcn_s_barrier();
        stage(SM0, kb + 2*BK);
        asm volatile("s_waitcnt vmcnt(6)" ::: "memory");
        __builtin_amdgcn_s_barrier();
        compute(SM1);
        __builtin_amdgcn_s_barrier();
    }
    // tail: SM0 holds k=30 (in flight), k=31 to stage
    stage(SM1, 31*BK);
    asm volatile("s_waitcnt vmcnt(6)" ::: "memory");
    __builtin_amdgcn_s_barrier();
    compute(SM0);                                   // k=30
    __builtin_amdgcn_s_barrier();
    asm volatile("s_waitcnt vmcnt(0)" ::: "memory");
    __builtin_amdgcn_s_barrier();
    compute(SM1);                                   // k=31

    #pragma unroll
    for (int mt = 0; mt < 4; mt++) {
        #pragma unroll
        for (int r = 0; r < 4; r++) {
            int row = mt*16 + quad*4 + r;
            if (m0 + row < ce) {
                int t = tok[m0 + row];
                float s = twT[(size_t)e*N_TOK + t];
                #pragma unroll
                for (int nt = 0; nt < 2; nt++) {
                    int col = wave*32 + nt*16 + l16;
                    buf2[(size_t)(abase + row)*DIM + n0 + col] = acc[mt][nt][r] * s;
                }
            }
        }
    }
}

// ---------------- gather: out[t] = sum of buf2 rows for t's active experts ----------------
__global__ __launch_bounds__(128) void gather_kernel(void* ws, float* __restrict__ out)
{
    int t = blockIdx.x;
    int tid = threadIdx.x;
    const int* slot_of = ws_i32(ws, WS_SLOT);
    const float* buf2 = (const float*)((char*)ws + WS_BUF2);

    int d = tid * 4;
    float4 acc = {0.f, 0.f, 0.f, 0.f};
    #pragma unroll
    for (int e = 0; e < NE; e++) {
        int s = slot_of[e*N_TOK + t];      // wave-uniform per block
        if (s >= 0) {
            float4 v = *(const float4*)(buf2 + (size_t)s*DIM + d);
            acc.x += v.x; acc.y += v.y; acc.z += v.z; acc.w += v.w;
        }
    }
    *(float4*)(out + (size_t)t*DIM + d) = acc;
}

extern "C" void kernel_launch(void* const* d_in, const int* in_sizes, int n_in,
                              void* d_out, int out_size, void* d_ws, size_t ws_size,
                              hipStream_t stream)
{
    const float* x     = (const float*)d_in[0];
    const float* Wr    = (const float*)d_in[1];
    const float* br    = (const float*)d_in[2];
    const float* Wgate = (const float*)d_in[3];
    const float* bgate = (const float*)d_in[4];
    const float* W1    = (const float*)d_in[5];
    const float* W3    = (const float*)d_in[6];
    const float* W2    = (const float*)d_in[7];
    float* out = (float*)d_out;

    prep_kernel<<<640, 1024, 0, stream>>>(x, Wr, br, Wgate, bgate, W1, W3, d_ws);
    expert_scan_kernel<<<1, 1024, 0, stream>>>(d_ws);
    gemm1_fast<<<dim3(HID/BN, N_TOK/BM, NE + 1), 256, 0, stream>>>(W2, d_ws);
    gemm2_fast<<<dim3(DIM/BN, N_TOK/BM, NE), 256, 0, stream>>>(d_ws);
    gather_kernel<<<N_TOK, 128, 0, stream>>>(d_ws, out);
}

// Round 7
// 322.320 us; speedup vs baseline: 1.1121x; 1.0030x over previous
//
#include <hip/hip_runtime.h>
#include <math.h>

typedef unsigned short u16;
typedef unsigned int   u32;
typedef short s16x8 __attribute__((ext_vector_type(8)));
typedef float f32x4 __attribute__((ext_vector_type(4)));

#define N_TOK 2048
#define DIM   512
#define HID   2048
#define NE    16
#define NG    4
#define EPG   4
#define MAXT  2048

#define BM 128
#define BN 128
#define BK 64

// ---- workspace layout (bytes) ----
#define WS_CNT    0                              // 16 ints
#define WS_OFF    128                            // 17 ints
#define WS_TOKIDX 256                            // 16*2048 ints
#define WS_TW     (WS_TOKIDX + NE*MAXT*4)        // twT[e][t]: 16*2048 f32
#define WS_XB     (WS_TW + N_TOK*NE*4)           // 2048*512 u16 (bf16 x)
#define WS_HBUF   (WS_XB + (size_t)N_TOK*DIM*2)  // 8192*2048 u16
#define WS_W1T    (WS_HBUF + (size_t)8192*HID*2) // 16*2048*512 u16 (bf16 W1^T [e][n][k])
#define WS_W3T    (WS_W1T + (size_t)NE*HID*DIM*2)
#define WS_W2T    (WS_W3T + (size_t)NE*HID*DIM*2) // 16*512*2048 u16 (bf16 W2^T [e][n][k])
#define WS_SLOT   (WS_W2T + (size_t)NE*DIM*HID*2) // slot_of[e][t]: 16*2048 ints
// buf2 (8192*512 f32 = 16.8 MB) aliases W1T: W1T is dead once gemm1 completes,
// buf2 is written by gemm2 (after gemm1) and read by gather. Safe within one call
// and across graph replays (prep rewrites W1T first each call).
#define WS_BUF2   WS_W1T

__device__ __forceinline__ int* ws_i32(void* ws, size_t off) { return (int*)((char*)ws + off); }

__device__ __forceinline__ u16 f2b(float f) {   // fp32 -> bf16 RNE
    union { float f; u32 i; } v; v.f = f;
    u32 b = v.i;
    u32 r = b + 0x7FFFu + ((b >> 16) & 1u);
    return (u16)(r >> 16);
}

// async global->LDS, 16B/lane; LDS side is wave-uniform base + lane*16
__device__ __forceinline__ void gl_lds16(const u16* g, u16* l) {
    __builtin_amdgcn_global_load_lds((const __attribute__((address_space(1))) void*)g,
                                     (__attribute__((address_space(3))) void*)l, 16, 0, 0);
}

// ---------------- prep: routing (128 blocks) + W1/W3 convert-transpose (512 blocks) ----------------
__global__ __launch_bounds__(1024) void prep_kernel(
    const float* __restrict__ x, const float* __restrict__ Wr, const float* __restrict__ br,
    const float* __restrict__ Wgate, const float* __restrict__ bgate,
    const float* __restrict__ W1, const float* __restrict__ W3, void* ws)
{
    __shared__ u16 T[2][128*128];   // 2 x 32 KB (transpose path only)
    int tid = threadIdx.x;
    int bid = blockIdx.x;

    if (bid < 128) {
        // ---- routing: 16 waves, one token per wave ----
        int t = bid * 16 + (tid >> 6);
        int lane = tid & 63;

        float xl[8];
        {
            const float4* xr = (const float4*)(x + (size_t)t*DIM + lane*8);
            float4 a = xr[0], b = xr[1];
            xl[0]=a.x; xl[1]=a.y; xl[2]=a.z; xl[3]=a.w;
            xl[4]=b.x; xl[5]=b.y; xl[6]=b.z; xl[7]=b.w;
        }
        {
            union { u16 h[8]; uint4 q; } pk;
            #pragma unroll
            for (int i = 0; i < 8; i++) pk.h[i] = f2b(xl[i]);
            u16* xb = (u16*)((char*)ws + WS_XB);
            *(uint4*)(xb + (size_t)t*DIM + lane*8) = pk.q;
        }

        float gl[NG] = {0.f,0.f,0.f,0.f};
        float el[NE];
        #pragma unroll
        for (int e = 0; e < NE; e++) el[e] = 0.f;

        {
            const float4* Wr4 = (const float4*)Wr;
            #pragma unroll
            for (int c = 0; c < 8; c++) {
                float4 w = Wr4[lane*8 + c];
                gl[0] += xl[c]*w.x; gl[1] += xl[c]*w.y;
                gl[2] += xl[c]*w.z; gl[3] += xl[c]*w.w;
            }
        }
        {
            const float4* Wg4 = (const float4*)Wgate;
            #pragma unroll
            for (int g = 0; g < NG; g++) {
                #pragma unroll
                for (int c = 0; c < 8; c++) {
                    float4 w = Wg4[(size_t)g*DIM + lane*8 + c];
                    el[g*4+0] += xl[c]*w.x; el[g*4+1] += xl[c]*w.y;
                    el[g*4+2] += xl[c]*w.z; el[g*4+3] += xl[c]*w.w;
                }
            }
        }

        #pragma unroll
        for (int g = 0; g < NG; g++)
            #pragma unroll
            for (int s = 32; s; s >>= 1) gl[g] += __shfl_xor(gl[g], s);
        #pragma unroll
        for (int e = 0; e < NE; e++)
            #pragma unroll
            for (int s = 32; s; s >>= 1) el[e] += __shfl_xor(el[e], s);

        if (lane != 0) return;

        float gp[NG];
        float mx = -1e30f;
        #pragma unroll
        for (int g = 0; g < NG; g++) { gl[g] += br[g]; mx = fmaxf(mx, gl[g]); }
        float sum = 0.f;
        #pragma unroll
        for (int g = 0; g < NG; g++) { gp[g] = expf(gl[g] - mx); sum += gp[g]; }
        #pragma unroll
        for (int g = 0; g < NG; g++) gp[g] /= sum;

        int i0 = 0;
        #pragma unroll
        for (int g = 1; g < NG; g++) if (gp[g] > gp[i0]) i0 = g;
        int i1 = -1;
        #pragma unroll
        for (int g = 0; g < NG; g++) { if (g == i0) continue; if (i1 < 0 || gp[g] > gp[i1]) i1 = g; }

        bool act1 = (gp[i0] + gp[i1]) <= 0.9f;
        float mp0 = gp[i0], mp1 = act1 ? gp[i1] : 0.f;
        float inv = 1.f / (mp0 + mp1 + 1e-9f);
        float wg[NG] = {0.f,0.f,0.f,0.f};
        wg[i0] = mp0 * inv;
        wg[i1] = mp1 * inv;

        float tw[NE];
        #pragma unroll
        for (int g = 0; g < NG; g++) {
            float ep[EPG];
            float emx = -1e30f;
            #pragma unroll
            for (int j = 0; j < EPG; j++) {
                float v = el[g*4 + j] + bgate[g*4 + j];
                ep[j] = v; emx = fmaxf(emx, v);
            }
            float es = 0.f;
            #pragma unroll
            for (int j = 0; j < EPG; j++) { ep[j] = expf(ep[j] - emx); es += ep[j]; }
            #pragma unroll
            for (int j = 0; j < EPG; j++) ep[j] /= es;

            int j0 = 0;
            #pragma unroll
            for (int j = 1; j < EPG; j++) if (ep[j] > ep[j0]) j0 = j;
            int j1 = -1;
            #pragma unroll
            for (int j = 0; j < EPG; j++) { if (j == j0) continue; if (j1 < 0 || ep[j] > ep[j1]) j1 = j; }

            bool ea1 = (ep[j0] + ep[j1]) <= 0.9f;
            float e0 = ep[j0], e1 = ea1 ? ep[j1] : 0.f;
            float einv = 1.f / (e0 + e1 + 1e-9f);
            float we[EPG] = {0.f,0.f,0.f,0.f};
            we[j0] = e0 * einv;
            we[j1] = e1 * einv;
            #pragma unroll
            for (int j = 0; j < EPG; j++) tw[g*4 + j] = wg[g] * we[j] * 0.5f;   // SCALE = 1/sqrt(4)
        }

        float* twT = (float*)((char*)ws + WS_TW);
        #pragma unroll
        for (int e = 0; e < NE; e++) twT[(size_t)e*N_TOK + t] = tw[e];
        return;
    }

    // ---- W1/W3 convert+transpose: 512 blocks x 4 tiles of 128k x 128n ----
    int bx = bid - 128;
    int j = tid & 31, i0 = tid >> 5;     // j: n-micro (coalesced read), i0: k-micro
    int tg0 = bx * 4;                    // 2048 tiles (2 mats x 16 e x 64)

    const float* src; u16* dst; int k0, n0;
    float4 v0, v1, v2, v3;

    auto setup = [&](int tg) {
        int mat = tg >> 10, e = (tg >> 6) & 15, w = tg & 63;
        const float* s  = mat ? W3 : W1;
        u16* d = (u16*)((char*)ws + (mat ? WS_W3T : WS_W1T));
        k0 = (w & 3) << 7; n0 = (w >> 2) << 7;   // K=512: 4 k-tiles; N=2048: 16 n-tiles
        src = s + (size_t)e*DIM*HID + (size_t)(k0 + 4*i0)*HID + n0 + 4*j;
        dst = d + (size_t)e*HID*DIM;
    };
    auto issue_loads = [&]() {           // 4 x float4, 512B-contiguous segments
        v0 = *(const float4*)(src);
        v1 = *(const float4*)(src + HID);
        v2 = *(const float4*)(src + 2*HID);
        v3 = *(const float4*)(src + 3*HID);
    };

    setup(tg0);
    issue_loads();

    for (int it = 0; it < 4; ++it) {
        u16* dstc = dst; int k0c = k0, n0c = n0;
        u16* Tb = &T[it & 1][0];

        int pc = 4 * (i0 ^ ((j & 15) << 1));
        union { u16 h[4]; uint2 q; } p;
        p.h[0]=f2b(v0.x); p.h[1]=f2b(v1.x); p.h[2]=f2b(v2.x); p.h[3]=f2b(v3.x);
        *(uint2*)(&Tb[(4*j+0)*128 + pc]) = p.q;
        p.h[0]=f2b(v0.y); p.h[1]=f2b(v1.y); p.h[2]=f2b(v2.y); p.h[3]=f2b(v3.y);
        *(uint2*)(&Tb[(4*j+1)*128 + pc]) = p.q;
        p.h[0]=f2b(v0.z); p.h[1]=f2b(v1.z); p.h[2]=f2b(v2.z); p.h[3]=f2b(v3.z);
        *(uint2*)(&Tb[(4*j+2)*128 + pc]) = p.q;
        p.h[0]=f2b(v0.w); p.h[1]=f2b(v1.w); p.h[2]=f2b(v2.w); p.h[3]=f2b(v3.w);
        *(uint2*)(&Tb[(4*j+3)*128 + pc]) = p.q;

        if (it + 1 < 4) { setup(tg0 + it + 1); issue_loads(); }

        asm volatile("s_waitcnt lgkmcnt(0)" ::: "memory");
        __builtin_amdgcn_s_barrier();

        #pragma unroll
        for (int ph = 0; ph < 2; ++ph) {
            int idx = tid + ph*1024;
            int nr = idx >> 4, sg = idx & 15;
            int cp = (2*sg) ^ (((nr >> 2) & 15) << 1);
            *(s16x8*)(dstc + (size_t)(n0c+nr)*DIM + k0c + sg*8) = *(const s16x8*)(&Tb[nr*128 + 4*cp]);
        }
    }
}

// ---- expert lists + scan + slot map: 16 waves, two ballot passes, no atomics ----
__global__ __launch_bounds__(1024) void expert_scan_kernel(void* ws)
{
    int tid = threadIdx.x;
    int e = tid >> 6, lane = tid & 63;
    const float* twT = (const float*)((char*)ws + WS_TW) + (size_t)e*N_TOK;
    int* tok = ws_i32(ws, WS_TOKIDX) + e*MAXT;
    __shared__ int scnt[NE];
    __shared__ int soff[NE+1];

    float v[32];
    #pragma unroll
    for (int r = 0; r < 32; r++) v[r] = twT[r*64 + lane];

    unsigned long long lanemask = (1ull << lane) - 1ull;
    int base = 0;
    #pragma unroll
    for (int r = 0; r < 32; r++) {
        bool a = v[r] > 0.f;
        unsigned long long m = __ballot(a);
        if (a) tok[base + __popcll(m & lanemask)] = r*64 + lane;
        base += __popcll(m);
    }
    if (lane == 0) scnt[e] = base;
    __syncthreads();
    if (tid == 0) {
        int* cnt = ws_i32(ws, WS_CNT);
        int* off = ws_i32(ws, WS_OFF);
        int s = 0;
        for (int i = 0; i < NE; i++) { cnt[i] = scnt[i]; off[i] = s; soff[i] = s; s += scnt[i]; }
        off[NE] = s; soff[NE] = s;
    }
    __syncthreads();

    // pass 2: global slot per (e,t), -1 if inactive
    int* slot_of = ws_i32(ws, WS_SLOT) + e*N_TOK;
    int base2 = soff[e];
    #pragma unroll
    for (int r = 0; r < 32; r++) {
        bool a = v[r] > 0.f;
        unsigned long long m = __ballot(a);
        int pre = __popcll(m & lanemask);
        slot_of[r*64 + lane] = a ? (base2 + pre) : -1;
        base2 += __popcll(m);
    }
}

// ---------------- GEMM1 + W2 transpose (z==NE): hbuf = bf16( silu(X W1) * (X W3) ) ----------------
// Round-7: 128x128 tile, 512 threads (8 waves, 2x4), halves weight re-read
// amplification (8->4) and doubles MFMA per staged byte. Static ping-pong
// double-buffer with counted vmcnt(6) across raw s_barrier. LDS 2x48KB = 96KB.
__global__ __launch_bounds__(512) void gemm1_fast(const float* __restrict__ W2, void* ws)
{
    __shared__ __align__(16) u16 SM[49152];   // 96 KB: 2 x (As 16KB | Bs0 16KB | Bs1 16KB)
    int z = blockIdx.z;
    int tid = threadIdx.x;

    if (z == NE) {
        // ---- W2 [e][2048k][512n] fp32 -> W2T [e][512n][2048k] bf16, 4 tiles of 128x128 ----
        u16* T2 = SM;                              // first 32 KB
        u16* W2T = (u16*)((char*)ws + WS_W2T);
        int slot = blockIdx.x + 16*blockIdx.y;     // [0,256)
        int j = tid & 31, i = tid >> 5;            // j: n-micro [0,32), i: k-micro [0,16)
        #pragma unroll 1
        for (int tt = 0; tt < 4; ++tt) {
            int tile = slot + tt*256;              // [0,1024)
            int e = tile >> 6, w = tile & 63;
            int k0 = (w & 15) << 7, n0 = (w >> 4) << 7;   // K=2048: 16 k-tiles; N=512: 4 n-tiles
            const float* s = W2 + (size_t)e*HID*DIM + (size_t)k0*DIM + n0 + 4*j;
            if (tt) __syncthreads();
            #pragma unroll
            for (int c = 0; c < 2; ++c) {
                int kb = 4*i + 64*c;
                const float* base = s + (size_t)kb*DIM;
                float4 v0 = *(const float4*)(base);
                float4 v1 = *(const float4*)(base + DIM);
                float4 v2 = *(const float4*)(base + 2*DIM);
                float4 v3 = *(const float4*)(base + 3*DIM);
                int pc = 4 * ((i + 16*c) ^ ((j & 15) << 1));
                union { u16 h[4]; uint2 q; } p;
                p.h[0]=f2b(v0.x); p.h[1]=f2b(v1.x); p.h[2]=f2b(v2.x); p.h[3]=f2b(v3.x);
                *(uint2*)(&T2[(4*j+0)*128 + pc]) = p.q;
                p.h[0]=f2b(v0.y); p.h[1]=f2b(v1.y); p.h[2]=f2b(v2.y); p.h[3]=f2b(v3.y);
                *(uint2*)(&T2[(4*j+1)*128 + pc]) = p.q;
                p.h[0]=f2b(v0.z); p.h[1]=f2b(v1.z); p.h[2]=f2b(v2.z); p.h[3]=f2b(v3.z);
                *(uint2*)(&T2[(4*j+2)*128 + pc]) = p.q;
                p.h[0]=f2b(v0.w); p.h[1]=f2b(v1.w); p.h[2]=f2b(v2.w); p.h[3]=f2b(v3.w);
                *(uint2*)(&T2[(4*j+3)*128 + pc]) = p.q;
            }
            __syncthreads();
            u16* d = W2T + (size_t)e*DIM*HID;
            #pragma unroll
            for (int ph = 0; ph < 4; ++ph) {
                int idx = tid + ph*512;
                int nr = idx >> 4, sg = idx & 15;
                int cp = (2*sg) ^ (((nr >> 2) & 15) << 1);
                *(s16x8*)(d + (size_t)(n0+nr)*HID + k0 + sg*8) = *(const s16x8*)(&T2[nr*128 + 4*cp]);
            }
        }
        return;
    }

    int e  = z;
    const int* cnt = ws_i32(ws, WS_CNT);
    int ce = cnt[e];
    int m0 = blockIdx.y * BM;
    if (m0 >= ce) return;
    int n0 = blockIdx.x * BN;

    const int* off = ws_i32(ws, WS_OFF);
    const int* tok = ws_i32(ws, WS_TOKIDX) + e*MAXT;
    const u16* xb  = (const u16*)((char*)ws + WS_XB);
    const u16* W1T = (const u16*)((char*)ws + WS_W1T) + (size_t)e*HID*DIM;  // [n][k]
    const u16* W3T = (const u16*)((char*)ws + WS_W3T) + (size_t)e*HID*DIM;
    u16* hbuf = (u16*)((char*)ws + WS_HBUF);
    int obase = off[e] + m0;

    int wave = tid >> 6, lane = tid & 63;
    int wr = wave >> 2, wc = wave & 3;      // 2x4 wave grid; wave tile 64m x 32n
    int quad = lane >> 4, l16 = lane & 15;
    int swz  = l16 & 7;
    int r8 = lane >> 3, sg = lane & 7;
    int swk = ((sg ^ r8) << 3);      // swizzle folded into global k-offset

    // A rows m = m0 + wave*16 + {0,8} + r8, clamped; B rows n = n0 + wave*16 + {0,8} + r8
    int m_a0 = m0 + wave*16 + r8;     if (m_a0 >= ce) m_a0 = ce - 1;
    int m_a1 = m0 + wave*16 + 8 + r8; if (m_a1 >= ce) m_a1 = ce - 1;
    const u16* arow0 = xb + (size_t)tok[m_a0]*DIM + swk;
    const u16* arow1 = xb + (size_t)tok[m_a1]*DIM + swk;
    const u16* b1r0 = W1T + (size_t)(n0 + wave*16 + r8)*DIM + swk;
    const u16* b1r1 = W1T + (size_t)(n0 + wave*16 + 8 + r8)*DIM + swk;
    const u16* b3r0 = W3T + (size_t)(n0 + wave*16 + r8)*DIM + swk;
    const u16* b3r1 = W3T + (size_t)(n0 + wave*16 + 8 + r8)*DIM + swk;

    f32x4 acc1[4][2], acc3[4][2];
    #pragma unroll
    for (int mt = 0; mt < 4; mt++)
        #pragma unroll
        for (int nt = 0; nt < 2; nt++) {
            acc1[mt][nt] = (f32x4){0.f,0.f,0.f,0.f};
            acc3[mt][nt] = (f32x4){0.f,0.f,0.f,0.f};
        }

    // buffer (u16): As 8192 | Bs0 8192 | Bs1 8192 ; buf1 at +24576
    auto stage = [&](u16* B, int k0) {
        gl_lds16(arow0 + k0, B + (wave*16)*BK);
        gl_lds16(arow1 + k0, B + (wave*16 + 8)*BK);
        gl_lds16(b1r0 + k0, B + 8192 + (wave*16)*BK);
        gl_lds16(b1r1 + k0, B + 8192 + (wave*16 + 8)*BK);
        gl_lds16(b3r0 + k0, B + 16384 + (wave*16)*BK);
        gl_lds16(b3r1 + k0, B + 16384 + (wave*16 + 8)*BK);
    };
    auto compute = [&](const u16* B) {
        #pragma unroll
        for (int kk = 0; kk < BK; kk += 32) {
            int jj = (kk >> 3) + quad;
            int so = ((jj ^ swz) << 3);
            s16x8 af[4];
            #pragma unroll
            for (int mt = 0; mt < 4; mt++)
                af[mt] = *(const s16x8*)(B + (wr*64 + mt*16 + l16)*BK + so);
            #pragma unroll
            for (int nt = 0; nt < 2; nt++) {
                int n = wc*32 + nt*16 + l16;
                s16x8 b1 = *(const s16x8*)(B + 8192 + n*BK + so);
                s16x8 b3 = *(const s16x8*)(B + 16384 + n*BK + so);
                #pragma unroll
                for (int mt = 0; mt < 4; mt++) {
                    acc1[mt][nt] = __builtin_amdgcn_mfma_f32_16x16x32_bf16(af[mt], b1, acc1[mt][nt], 0, 0, 0);
                    acc3[mt][nt] = __builtin_amdgcn_mfma_f32_16x16x32_bf16(af[mt], b3, acc3[mt][nt], 0, 0, 0);
                }
            }
        }
    };

    u16* SM0 = SM;
    u16* SM1 = SM + 24576;

    stage(SM0, 0);
    #pragma unroll 1
    for (int kt2 = 0; kt2 < 3; ++kt2) {             // K-steps 0..5
        int kb = kt2*2*BK;
        stage(SM1, kb + BK);
        asm volatile("s_waitcnt vmcnt(6)" ::: "memory");
        __builtin_amdgcn_s_barrier();
        compute(SM0);
        __builtin_amdgcn_s_barrier();
        stage(SM0, kb + 2*BK);
        asm volatile("s_waitcnt vmcnt(6)" ::: "memory");
        __builtin_amdgcn_s_barrier();
        compute(SM1);
        __builtin_amdgcn_s_barrier();
    }
    // tail: SM0 holds k=6 (in flight), stage k=7
    stage(SM1, 7*BK);
    asm volatile("s_waitcnt vmcnt(6)" ::: "memory");
    __builtin_amdgcn_s_barrier();
    compute(SM0);                                   // k=6
    __builtin_amdgcn_s_barrier();
    asm volatile("s_waitcnt vmcnt(0)" ::: "memory");
    __builtin_amdgcn_s_barrier();
    compute(SM1);                                   // k=7

    #pragma unroll
    for (int mt = 0; mt < 4; mt++) {
        #pragma unroll
        for (int r = 0; r < 4; r++) {
            int row = wr*64 + mt*16 + quad*4 + r;
            if (m0 + row < ce) {
                #pragma unroll
                for (int nt = 0; nt < 2; nt++) {
                    float a = acc1[mt][nt][r];
                    float b = acc3[mt][nt][r];
                    float h = (a / (1.f + expf(-a))) * b;
                    int col = wc*32 + nt*16 + l16;
                    hbuf[(size_t)(obase + row)*HID + n0 + col] = f2b(h);
                }
            }
        }
    }
}

// ---------------- GEMM2: buf2 = tw * (h W2), 128x128 tile, 512 threads ----------------
__global__ __launch_bounds__(512) void gemm2_fast(void* ws)
{
    __shared__ __align__(16) u16 SM[32768];   // 64 KB: 2 x (As 16KB | Bs 16KB)
    int e  = blockIdx.z;
    const int* cnt = ws_i32(ws, WS_CNT);
    int ce = cnt[e];
    int m0 = blockIdx.y * BM;
    if (m0 >= ce) return;
    int n0 = blockIdx.x * BN;

    const int* off = ws_i32(ws, WS_OFF);
    const int* tok = ws_i32(ws, WS_TOKIDX) + e*MAXT;
    const float* twT = (const float*)((char*)ws + WS_TW);
    const u16* hbuf = (const u16*)((char*)ws + WS_HBUF);
    const u16* W2T = (const u16*)((char*)ws + WS_W2T) + (size_t)e*DIM*HID;  // [n=512][k=2048]
    float* buf2 = (float*)((char*)ws + WS_BUF2);
    int abase = off[e] + m0;
    int total = off[NE];

    int tid = threadIdx.x;
    int wave = tid >> 6, lane = tid & 63;
    int wr = wave >> 2, wc = wave & 3;
    int quad = lane >> 4, l16 = lane & 15;
    int swz  = l16 & 7;
    int r8 = lane >> 3, sg = lane & 7;
    int swk = ((sg ^ r8) << 3);

    int ar0 = abase + wave*16 + r8;      if (ar0 > total - 1) ar0 = total - 1;
    int ar1 = abase + wave*16 + 8 + r8;  if (ar1 > total - 1) ar1 = total - 1;
    const u16* arow0 = hbuf + (size_t)ar0*HID + swk;
    const u16* arow1 = hbuf + (size_t)ar1*HID + swk;
    const u16* br0 = W2T + (size_t)(n0 + wave*16 + r8)*HID + swk;
    const u16* br1 = W2T + (size_t)(n0 + wave*16 + 8 + r8)*HID + swk;

    f32x4 acc[4][2];
    #pragma unroll
    for (int mt = 0; mt < 4; mt++)
        #pragma unroll
        for (int nt = 0; nt < 2; nt++) acc[mt][nt] = (f32x4){0.f,0.f,0.f,0.f};

    // buffer (u16): As 8192 | Bs 8192 ; buf1 at +16384
    auto stage = [&](u16* B, int k0) {
        gl_lds16(arow0 + k0, B + (wave*16)*BK);
        gl_lds16(arow1 + k0, B + (wave*16 + 8)*BK);
        gl_lds16(br0 + k0, B + 8192 + (wave*16)*BK);
        gl_lds16(br1 + k0, B + 8192 + (wave*16 + 8)*BK);
    };
    auto compute = [&](const u16* B) {
        #pragma unroll
        for (int kk = 0; kk < BK; kk += 32) {
            int jj = (kk >> 3) + quad;
            int so = ((jj ^ swz) << 3);
            s16x8 af[4];
            #pragma unroll
            for (int mt = 0; mt < 4; mt++)
                af[mt] = *(const s16x8*)(B + (wr*64 + mt*16 + l16)*BK + so);
            #pragma unroll
            for (int nt = 0; nt < 2; nt++) {
                int n = wc*32 + nt*16 + l16;
                s16x8 bfr = *(const s16x8*)(B + 8192 + n*BK + so);
                #pragma unroll
                for (int mt = 0; mt < 4; mt++)
                    acc[mt][nt] = __builtin_amdgcn_mfma_f32_16x16x32_bf16(af[mt], bfr, acc[mt][nt], 0, 0, 0);
            }
        }
    };

    u16* SM0 = SM;
    u16* SM1 = SM + 16384;

    stage(SM0, 0);
    #pragma unroll 1
    for (int kt2 = 0; kt2 < 15; ++kt2) {            // K-steps 0..29
        int kb = kt2*2*BK;
        stage(SM1, kb + BK);
        asm volatile("s_waitcnt vmcnt(4)" ::: "memory");
        __builtin_amdgcn_s_barrier();
        compute(SM0);
        __builtin_amdgcn_s_barrier();
        stage(SM0, kb + 2*BK);
        asm volatile("s_waitcnt vmcnt(4)" ::: "memory");
        __builtin_amdgcn_s_barrier();
        compute(SM1);
        __builtin_amdgcn_s_barrier();
    }
    // tail: SM0 holds k=30 (in flight), stage k=31
    stage(SM1, 31*BK);
    asm volatile("s_waitcnt vmcnt(4)" ::: "memory");
    __builtin_amdgcn_s_barrier();
    compute(SM0);                                   // k=30
    __builtin_amdgcn_s_barrier();
    asm volatile("s_waitcnt vmcnt(0)" ::: "memory");
    __builtin_amdgcn_s_barrier();
    compute(SM1);                                   // k=31

    #pragma unroll
    for (int mt = 0; mt < 4; mt++) {
        #pragma unroll
        for (int r = 0; r < 4; r++) {
            int row = wr*64 + mt*16 + quad*4 + r;
            if (m0 + row < ce) {
                int t = tok[m0 + row];
                float s = twT[(size_t)e*N_TOK + t];
                #pragma unroll
                for (int nt = 0; nt < 2; nt++) {
                    int col = wc*32 + nt*16 + l16;
                    buf2[(size_t)(abase + row)*DIM + n0 + col] = acc[mt][nt][r] * s;
                }
            }
        }
    }
}

// ---------------- gather: out[t] = sum of buf2 rows for t's active experts ----------------
__global__ __launch_bounds__(128) void gather_kernel(void* ws, float* __restrict__ out)
{
    int t = blockIdx.x;
    int tid = threadIdx.x;
    const int* slot_of = ws_i32(ws, WS_SLOT);
    const float* buf2 = (const float*)((char*)ws + WS_BUF2);

    int d = tid * 4;
    float4 acc = {0.f, 0.f, 0.f, 0.f};
    #pragma unroll
    for (int e = 0; e < NE; e++) {
        int s = slot_of[e*N_TOK + t];      // wave-uniform per block
        if (s >= 0) {
            float4 v = *(const float4*)(buf2 + (size_t)s*DIM + d);
            acc.x += v.x; acc.y += v.y; acc.z += v.z; acc.w += v.w;
        }
    }
    *(float4*)(out + (size_t)t*DIM + d) = acc;
}

extern "C" void kernel_launch(void* const* d_in, const int* in_sizes, int n_in,
                              void* d_out, int out_size, void* d_ws, size_t ws_size,
                              hipStream_t stream)
{
    const float* x     = (const float*)d_in[0];
    const float* Wr    = (const float*)d_in[1];
    const float* br    = (const float*)d_in[2];
    const float* Wgate = (const float*)d_in[3];
    const float* bgate = (const float*)d_in[4];
    const float* W1    = (const float*)d_in[5];
    const float* W3    = (const float*)d_in[6];
    const float* W2    = (const float*)d_in[7];
    float* out = (float*)d_out;

    prep_kernel<<<640, 1024, 0, stream>>>(x, Wr, br, Wgate, bgate, W1, W3, d_ws);
    expert_scan_kernel<<<1, 1024, 0, stream>>>(d_ws);
    gemm1_fast<<<dim3(HID/BN, N_TOK/BM, NE + 1), 512, 0, stream>>>(W2, d_ws);
    gemm2_fast<<<dim3(DIM/BN, N_TOK/BM, NE), 512, 0, stream>>>(d_ws);
    gather_kernel<<<N_TOK, 128, 0, stream>>>(d_ws, out);
}